// Round 2
// baseline (1417.987 us; speedup 1.0000x reference)
//
#include <hip/hip_runtime.h>
#include <hip/hip_bf16.h>

#define B_ 32
#define N_ 512
#define NB_ 10
#define E_ 1024
#define H_ 256
#define A_ 82
#define K_ 4
#define D_ 3
#define M_ (B_*N_)   // 16384 rows

__device__ __forceinline__ float b2f(unsigned short u){
    unsigned int x = ((unsigned int)u) << 16;
    return __builtin_bit_cast(float, x);
}
__device__ __forceinline__ unsigned short f2b(float f){
    unsigned int x = __builtin_bit_cast(unsigned int, f);
    unsigned int lsb = (x >> 16) & 1u;
    x += 0x7fffu + lsb;
    return (unsigned short)(x >> 16);
}
__device__ __forceinline__ float sigmoidf_(float x){ return 1.f/(1.f+expf(-x)); }

// ---- conversion table: 32 float tensors (all inputs except int anb/bnb) ----
// order: atom, bond, nbmask, dmask, Wv, bv, Wa_main, ba_main, Wa_super, ba_super,
//        Wm, bm, Wbmm, bbmm, Wm2s, bm2s, Ws2m, bs2m, Wsup, bsup, Wzm1, bzm1,
//        Wzm2, bzm2, Wzs1, bzs1, Wzs2, bzs2, Wu2, bu2, Wu1, bu1
static constexpr int CVT_N[32] = {
    B_*N_*A_, B_*E_*6, B_*N_*NB_, B_*N_,
    A_*H_, H_,
    D_*K_*H_*H_, D_*K_*H_, D_*K_*H_*H_, D_*K_*H_,
    D_*K_*H_*H_, D_*K_*H_, D_*K_*H_, D_*K_,
    D_*K_*H_*H_, D_*H_, D_*H_*H_, D_*H_,
    D_*H_*H_, D_*H_, D_*H_*H_, D_*H_,
    D_*H_*H_, D_*H_, D_*H_*H_, D_*H_,
    D_*H_*H_, D_*H_, D_*(H_+6)*H_, D_*H_,
    D_*2*H_*H_, D_*H_
};
struct Offs { long v[33]; };
static constexpr Offs mk_offs(){
    Offs o{}; o.v[0]=0;
    for(int i=0;i<32;i++) o.v[i+1]=o.v[i]+CVT_N[i];
    return o;
}
static constexpr Offs CVT_OFF = mk_offs();

struct Ptrs { const void* p[32]; };

// ---------------- dtype detection: bf16 vs f32 ----------------
__global__ void k_detect(const unsigned short* __restrict__ wv_raw, int* __restrict__ flag){
    float v = b2f(wv_raw[threadIdx.x]);
    bool plaus = (v==v) && (fabsf(v) < 100.0f);
    unsigned long long m = __ballot(plaus);
    if (threadIdx.x==0) *flag = (m == ~0ULL) ? 1 : 0;
}

// ---------------- convert all float inputs to fp32 workspace ----------------
__global__ void k_cvt(Ptrs ptrs, float* __restrict__ dst, const int* __restrict__ flag){
    int t = blockIdx.y;
    int n = CVT_N[t];
    int i4 = blockIdx.x*256 + threadIdx.x;
    if (i4*4 >= n) return;
    const void* src = ptrs.p[t];
    float4 o;
    if (*flag){
        ushort4 u = ((const ushort4*)src)[i4];
        o.x=b2f(u.x); o.y=b2f(u.y); o.z=b2f(u.z); o.w=b2f(u.w);
    } else {
        o = ((const float4*)src)[i4];
    }
    *(float4*)(dst + CVT_OFF.v[t] + (size_t)i4*4) = o;
}

// ---------------- vertex embedding: vf = lrelu(atom @ Wv + bv, 0.01) ----------------
__global__ void k_embed(const float* __restrict__ atom, const float* __restrict__ Wv,
                        const float* __restrict__ bv, float* __restrict__ vf){
    __shared__ float arow[A_];
    int row = blockIdx.x; int j = threadIdx.x;
    if (j < A_) arow[j] = atom[(size_t)row*A_ + j];
    __syncthreads();
    float acc = bv[j];
    for(int a=0;a<A_;a++) acc += arow[a]*Wv[a*H_ + j];
    vf[(size_t)row*H_ + j] = acc > 0.f ? acc : 0.01f*acc;
}

// ---------------- sf0 = sum_n vf * d_mask ----------------
__global__ void k_sf0(const float* __restrict__ vf, const float* __restrict__ dmask,
                      float* __restrict__ sf){
    int b = blockIdx.x, h = threadIdx.x;
    __shared__ float mk[N_];
    for(int n=threadIdx.x;n<N_;n+=256) mk[n] = dmask[b*N_+n];
    __syncthreads();
    float s=0.f;
    for(int n=0;n<N_;n++) s += mk[n]*vf[((size_t)b*N_+n)*H_ + h];
    sf[b*H_+h]=s;
}

// ---------------- per-layer super-side precompute (tiny, from sf) ----------------
__global__ void k_super_pre(int d, const float* __restrict__ sf,
    const float* __restrict__ Wa_super, const float* __restrict__ ba_super,
    const float* __restrict__ Wbmm,
    const float* __restrict__ Ws2m, const float* __restrict__ bs2m,
    const float* __restrict__ Wsup, const float* __restrict__ bsup,
    const float* __restrict__ Wzm2, const float* __restrict__ bzm2,
    float* __restrict__ asw, float* __restrict__ s2m, float* __restrict__ ssf,
    float* __restrict__ stm2)
{
    int b = blockIdx.x, j = threadIdx.x;
    __shared__ float sfl[H_], s2ml[H_];
    sfl[j] = sf[b*H_+j];
    __syncthreads();
    for(int k=0;k<K_;k++){
        const float* W = Wa_super + ((size_t)(d*K_+k))*H_*H_;
        float acc = ba_super[(d*K_+k)*H_ + j];
        for(int h=0;h<H_;h++) acc += sfl[h]*W[h*H_+j];
        asw[(b*K_+k)*H_+j] = tanhf(acc)*Wbmm[(d*K_+k)*H_+j];
    }
    {
        const float* W = Ws2m + (size_t)d*H_*H_;
        float acc = bs2m[d*H_+j];
        for(int h=0;h<H_;h++) acc += sfl[h]*W[h*H_+j];
        float v = tanhf(acc); s2m[b*H_+j]=v; s2ml[j]=v;
    }
    {
        const float* W = Wsup + (size_t)d*H_*H_;
        float acc = bsup[d*H_+j];
        for(int h=0;h<H_;h++) acc += sfl[h]*W[h*H_+j];
        ssf[b*H_+j] = tanhf(acc);
    }
    __syncthreads();
    {
        const float* W = Wzm2 + (size_t)d*H_*H_;
        float acc = bzm2[d*H_+j];
        for(int h=0;h<H_;h++) acc += s2ml[h]*W[h*H_+j];
        stm2[b*H_+j]=acc;
    }
}

// ---------------- shared fp32 GEMM core: 32 rows x 256 cols, K=256 ----------------
__device__ __forceinline__ void gemm_core(const float* __restrict__ A,
    const float* __restrict__ W,
    float acc[8][4], float (*Als)[36], float (*Wls)[256])
{
    int tid = threadIdx.x;
    int lr = tid>>3, lc=(tid&7)*4;
    int tx = tid&63, ty=tid>>6;
    #pragma unroll
    for(int i=0;i<8;i++)
        #pragma unroll
        for(int j=0;j<4;j++) acc[i][j]=0.f;
    for(int k0=0;k0<H_;k0+=32){
        float4 av = *(const float4*)(A + (size_t)lr*H_ + k0 + lc);
        Als[lr][lc+0]=av.x; Als[lr][lc+1]=av.y; Als[lr][lc+2]=av.z; Als[lr][lc+3]=av.w;
        #pragma unroll
        for(int t=0;t<8;t++){
            int lin = t*1024 + tid*4;
            int kk = lin>>8, c = lin&255;
            float4 wv = *(const float4*)(W + (size_t)(k0+kk)*H_ + c);
            Wls[kk][c+0]=wv.x; Wls[kk][c+1]=wv.y;
            Wls[kk][c+2]=wv.z; Wls[kk][c+3]=wv.w;
        }
        __syncthreads();
        #pragma unroll
        for(int kk=0;kk<32;kk++){
            float4 w4 = *(const float4*)(&Wls[kk][tx*4]);
            #pragma unroll
            for(int i=0;i<8;i++){
                float a = Als[ty*8+i][kk];
                acc[i][0] += a*w4.x; acc[i][1] += a*w4.y;
                acc[i][2] += a*w4.z; acc[i][3] += a*w4.w;
            }
        }
        __syncthreads();
    }
}

// ---------------- big fused GEMM over vf ----------------
// seg 0..3 : a_main head k -> fused attention score
// seg 4    : proj_u2  = vf @ Wu2[:H]        (bu2 folded into k_nei)
// seg 5    : proj_u1a = vf @ Wu1[:H] + bu1
__global__ __launch_bounds__(256) void k_gemm_big(int d, const float* __restrict__ vf,
    const float* __restrict__ Wa_main, const float* __restrict__ ba_main,
    const float* __restrict__ bbmm,
    const float* __restrict__ Wu2, const float* __restrict__ Wu1,
    const float* __restrict__ bu1,
    const float* __restrict__ asw, float* __restrict__ score,
    float* __restrict__ proj_u2, float* __restrict__ proj_u1a)
{
    __shared__ float Als[32][36];
    __shared__ float Wls[32][256];
    __shared__ float red[32][65];
    int m0 = blockIdx.x*32;
    int seg = blockIdx.y;
    int b = m0 >> 9;
    const float* W;
    if (seg < 4)       W = Wa_main + ((size_t)(d*K_+seg))*H_*H_;
    else if (seg == 4) W = Wu2 + (size_t)d*(H_+6)*H_;
    else               W = Wu1 + (size_t)d*2*H_*H_;
    float acc[8][4];
    gemm_core(vf + (size_t)m0*H_, W, acc, Als, Wls);
    int tid=threadIdx.x, tx=tid&63, ty=tid>>6;
    int c0 = tx*4, r0 = ty*8;
    if (seg < 4){
        float w4[4], bb[4];
        const float* aswp = asw + (size_t)(b*K_+seg)*H_;
        const float* bap = ba_main + (d*K_+seg)*H_;
        #pragma unroll
        for(int j=0;j<4;j++){ w4[j]=aswp[c0+j]; bb[j]=bap[c0+j]; }
        #pragma unroll
        for(int i=0;i<8;i++){
            float p=0.f;
            #pragma unroll
            for(int j=0;j<4;j++) p += tanhf(acc[i][j]+bb[j])*w4[j];
            red[r0+i][tx]=p;
        }
        __syncthreads();
        if (tid < 32){
            float s=0.f;
            for(int x=0;x<64;x++) s += red[tid][x];
            int n = (m0&511) + tid;
            score[(size_t)(b*K_+seg)*N_ + n] = s + bbmm[d*K_+seg];
        }
    } else {
        float* out = (seg==4)? proj_u2 : proj_u1a;
        float bb[4] = {0.f,0.f,0.f,0.f};
        if (seg==5){
            const float* bp = bu1 + d*H_;
            #pragma unroll
            for(int j=0;j<4;j++) bb[j]=bp[c0+j];
        }
        #pragma unroll
        for(int i=0;i<8;i++){
            float4 o;
            o.x = acc[i][0]+bb[0]; o.y = acc[i][1]+bb[1];
            o.z = acc[i][2]+bb[2]; o.w = acc[i][3]+bb[3];
            *(float4*)(out + (size_t)(m0+r0+i)*H_ + c0) = o;
        }
    }
}

// ---------------- masked softmax over n ----------------
__global__ void k_softmax(float* __restrict__ score, const float* __restrict__ dmask,
                          float* __restrict__ sumattn){
    int b = blockIdx.x, k = blockIdx.y;
    int tid = threadIdx.x;
    __shared__ float sh[256];
    float* a = score + (size_t)(b*K_+k)*N_;
    float v0 = a[tid], v1 = a[tid+256];
    sh[tid]=fmaxf(v0,v1); __syncthreads();
    for(int s=128;s>0;s>>=1){ if(tid<s) sh[tid]=fmaxf(sh[tid],sh[tid+s]); __syncthreads(); }
    float m = sh[0]; __syncthreads();
    float e0 = expf(v0-m)*dmask[b*N_+tid], e1 = expf(v1-m)*dmask[b*N_+tid+256];
    sh[tid]=e0+e1; __syncthreads();
    for(int s=128;s>0;s>>=1){ if(tid<s) sh[tid]+=sh[tid+s]; __syncthreads(); }
    float S = sh[0];
    float inv = 1.f/(S+1e-6f);
    a[tid]=e0*inv; a[tid+256]=e1*inv;
    if(tid==0) sumattn[b*K_+k]=S*inv;
}

// ---------------- t[b,k,:] = attn[b,k,:] @ vf[b] ----------------
__global__ void k_t(const float* __restrict__ attn, const float* __restrict__ vf,
                    float* __restrict__ tbuf){
    int b=blockIdx.x, k=blockIdx.y, h=threadIdx.x;
    __shared__ float at[N_];
    for(int n=h;n<N_;n+=256) at[n]=attn[(size_t)(b*K_+k)*N_+n];
    __syncthreads();
    float acc=0.f;
    for(int n=0;n<N_;n++) acc += at[n]*vf[((size_t)b*N_+n)*H_+h];
    tbuf[(b*K_+k)*H_+h]=acc;
}

// ---------------- m2s -> main_to_super -> sf GRU update ----------------
__global__ void k_m2s_sf(int d, const float* __restrict__ tbuf, const float* __restrict__ sumattn,
    const float* __restrict__ Wm, const float* __restrict__ bm,
    const float* __restrict__ Wm2s, const float* __restrict__ bm2s,
    const float* __restrict__ Wzs1, const float* __restrict__ bzs1,
    const float* __restrict__ Wzs2, const float* __restrict__ bzs2,
    const float* __restrict__ ssf, float* __restrict__ sf)
{
    int b=blockIdx.x, j=threadIdx.x;
    __shared__ float m2sl[K_][H_];
    __shared__ float mtsl[H_];
    __shared__ float ssl[H_];
    ssl[j]=ssf[b*H_+j];
    for(int k=0;k<K_;k++){
        const float* W = Wm + ((size_t)(d*K_+k))*H_*H_;
        float acc = sumattn[b*K_+k]*bm[(d*K_+k)*H_+j];
        const float* t = tbuf + (b*K_+k)*H_;
        for(int h=0;h<H_;h++) acc += t[h]*W[h*H_+j];
        m2sl[k][j]=acc;
    }
    __syncthreads();
    {
        const float* W = Wm2s + (size_t)d*(K_*H_)*H_;
        const float* m2f = &m2sl[0][0];
        float acc = bm2s[d*H_+j];
        for(int kh=0;kh<K_*H_;kh++) acc += m2f[kh]*W[(size_t)kh*H_+j];
        mtsl[j]=tanhf(acc);
    }
    __syncthreads();
    {
        const float* W1 = Wzs1 + (size_t)d*H_*H_;
        const float* W2 = Wzs2 + (size_t)d*H_*H_;
        float acc = bzs1[d*H_+j] + bzs2[d*H_+j];
        for(int h=0;h<H_;h++) acc += ssl[h]*W1[h*H_+j] + mtsl[h]*W2[h*H_+j];
        float z = sigmoidf_(acc);
        sf[b*H_+j] = (1.f-z)*ssl[j] + z*mtsl[j];
    }
}

// ---- nei = sum_j mask * lrelu(proj_u2[anb] + bond@Wu2[H:] + bu2, 0.1) ----
__global__ void k_nei(int d, const int* __restrict__ anb, const int* __restrict__ bnb,
    const float* __restrict__ nbm, const float* __restrict__ bond,
    const float* __restrict__ Wu2, const float* __restrict__ bu2,
    const float* __restrict__ proj_u2, float* __restrict__ nei)
{
    __shared__ float W2s[6][256];
    __shared__ float bfeat[NB_][6];
    __shared__ int ai[NB_]; __shared__ int bi[NB_]; __shared__ float mk[NB_];
    int row = blockIdx.x; int b = row >> 9; int h = threadIdx.x;
    const float* W2 = Wu2 + (size_t)d*(H_+6)*H_ + (size_t)H_*H_;
    for(int i=h;i<6*H_;i+=256) W2s[i>>8][i&255] = W2[i];
    if (h<NB_){ ai[h]=anb[row*NB_+h]; bi[h]=bnb[row*NB_+h]; mk[h]=nbm[row*NB_+h]; }
    __syncthreads();
    if (h<NB_*6){ int jn=h/6, i=h-jn*6; bfeat[jn][i]=bond[((size_t)b*E_+bi[jn])*6+i]; }
    __syncthreads();
    float bu = bu2[d*H_+h];
    float acc=0.f;
    #pragma unroll
    for(int jn=0;jn<NB_;jn++){
        float v = proj_u2[((size_t)b*N_+ai[jn])*H_+h] + bu;
        #pragma unroll
        for(int i=0;i<6;i++) v += bfeat[jn][i]*W2s[i][h];
        v = v>0.f? v : 0.1f*v;
        acc += mk[jn]*v;
    }
    nei[(size_t)row*H_+h]=acc;
}

// ---- main_self = lrelu(nei @ Wu1[H:] + proj_u1a, 0.1), in-place over proj_u1a ----
__global__ __launch_bounds__(256) void k_mainself(int d, const float* __restrict__ nei,
    const float* __restrict__ Wu1, float* __restrict__ pu){
    __shared__ float Als[32][36]; __shared__ float Wls[32][256];
    int m0=blockIdx.x*32;
    const float* W = Wu1 + (size_t)d*2*H_*H_ + (size_t)H_*H_;
    float acc[8][4];
    gemm_core(nei + (size_t)m0*H_, W, acc, Als, Wls);
    int tid=threadIdx.x, ty=tid>>6, c0=(tid&63)*4, r0=ty*8;
    #pragma unroll
    for(int i=0;i<8;i++){
        float4 base = *(const float4*)(pu + (size_t)(m0+r0+i)*H_ + c0);
        float4 o; float v;
        v=acc[i][0]+base.x; o.x = v>0.f?v:0.1f*v;
        v=acc[i][1]+base.y; o.y = v>0.f?v:0.1f*v;
        v=acc[i][2]+base.z; o.z = v>0.f?v:0.1f*v;
        v=acc[i][3]+base.w; o.w = v>0.f?v:0.1f*v;
        *(float4*)(pu + (size_t)(m0+r0+i)*H_ + c0) = o;
    }
}

// ---------------- z_main GEMM + GRU vf update ----------------
__global__ __launch_bounds__(256) void k_update(int d, const float* __restrict__ main_self,
    const float* __restrict__ Wzm1, const float* __restrict__ bzm1,
    const float* __restrict__ stm2, const float* __restrict__ s2m, float* __restrict__ vf){
    __shared__ float Als[32][36]; __shared__ float Wls[32][256];
    int m0=blockIdx.x*32; int b=m0>>9;
    float acc[8][4];
    gemm_core(main_self + (size_t)m0*H_, Wzm1 + (size_t)d*H_*H_, acc, Als, Wls);
    int tid=threadIdx.x, ty=tid>>6, c0=(tid&63)*4, r0=ty*8;
    float bz[4], st[4], sm[4];
    #pragma unroll
    for(int j=0;j<4;j++){
        bz[j]=bzm1[d*H_+c0+j]; st[j]=stm2[b*H_+c0+j]; sm[j]=s2m[b*H_+c0+j];
    }
    #pragma unroll
    for(int i=0;i<8;i++){
        float4 ms = *(const float4*)(main_self + (size_t)(m0+r0+i)*H_ + c0);
        float4 o; float z;
        z=sigmoidf_(acc[i][0]+bz[0]+st[0]); o.x=(1.f-z)*ms.x+z*sm[0];
        z=sigmoidf_(acc[i][1]+bz[1]+st[1]); o.y=(1.f-z)*ms.y+z*sm[1];
        z=sigmoidf_(acc[i][2]+bz[2]+st[2]); o.z=(1.f-z)*ms.z+z*sm[2];
        z=sigmoidf_(acc[i][3]+bz[3]+st[3]); o.w=(1.f-z)*ms.w+z*sm[3];
        *(float4*)(vf + (size_t)(m0+r0+i)*H_ + c0) = o;
    }
}

// ---------------- final output: [vf | sf], dtype per flag ----------------
__global__ void k_out(const float* __restrict__ vf, const float* __restrict__ sf,
                      void* __restrict__ out, const int* __restrict__ flag){
    int idx = blockIdx.x*256 + threadIdx.x;
    const int total = M_*H_ + B_*H_;
    if (idx >= total) return;
    float v = (idx < M_*H_) ? vf[idx] : sf[idx - M_*H_];
    if (*flag) ((unsigned short*)out)[idx] = f2b(v);
    else       ((float*)out)[idx] = v;
}

extern "C" void kernel_launch(void* const* d_in, const int* in_sizes, int n_in,
                              void* d_out, int out_size, void* d_ws, size_t ws_size,
                              hipStream_t stream)
{
    const int* anb = (const int*)d_in[2];
    const int* bnb = (const int*)d_in[3];

    // workspace layout (floats)
    float* ws   = (float*)d_ws;
    int*   flag = (int*)ws;                 // 256 B reserved
    float* cvt  = ws + 64;
    float* p    = cvt + ((CVT_OFF.v[32] + 63) & ~63L);
    float* vf        = p; p += (size_t)M_*H_;
    float* proj_u2   = p; p += (size_t)M_*H_;
    float* proj_u1a  = p; p += (size_t)M_*H_;   // becomes main_self in-place
    float* nei       = p; p += (size_t)M_*H_;
    float* sf        = p; p += B_*H_;
    float* score     = p; p += B_*K_*N_;
    float* sumattn   = p; p += B_*K_;
    float* asw       = p; p += B_*K_*H_;
    float* s2m       = p; p += B_*H_;
    float* ssf       = p; p += B_*H_;
    float* stm2      = p; p += B_*H_;
    float* tbuf      = p; p += B_*K_*H_;

    // converted fp32 tensors
    const float* cAtom = cvt + CVT_OFF.v[0];
    const float* cBond = cvt + CVT_OFF.v[1];
    const float* cNbm  = cvt + CVT_OFF.v[2];
    const float* cDm   = cvt + CVT_OFF.v[3];
    const float* cWv   = cvt + CVT_OFF.v[4];
    const float* cbv   = cvt + CVT_OFF.v[5];
    const float* cWam  = cvt + CVT_OFF.v[6];
    const float* cbam  = cvt + CVT_OFF.v[7];
    const float* cWas  = cvt + CVT_OFF.v[8];
    const float* cbas  = cvt + CVT_OFF.v[9];
    const float* cWm   = cvt + CVT_OFF.v[10];
    const float* cbm   = cvt + CVT_OFF.v[11];
    const float* cWbmm = cvt + CVT_OFF.v[12];
    const float* cbbmm = cvt + CVT_OFF.v[13];
    const float* cWm2s = cvt + CVT_OFF.v[14];
    const float* cbm2s = cvt + CVT_OFF.v[15];
    const float* cWs2m = cvt + CVT_OFF.v[16];
    const float* cbs2m = cvt + CVT_OFF.v[17];
    const float* cWsup = cvt + CVT_OFF.v[18];
    const float* cbsup = cvt + CVT_OFF.v[19];
    const float* cWzm1 = cvt + CVT_OFF.v[20];
    const float* cbzm1 = cvt + CVT_OFF.v[21];
    const float* cWzm2 = cvt + CVT_OFF.v[22];
    const float* cbzm2 = cvt + CVT_OFF.v[23];
    const float* cWzs1 = cvt + CVT_OFF.v[24];
    const float* cbzs1 = cvt + CVT_OFF.v[25];
    const float* cWzs2 = cvt + CVT_OFF.v[26];
    const float* cbzs2 = cvt + CVT_OFF.v[27];
    const float* cWu2  = cvt + CVT_OFF.v[28];
    const float* cbu2  = cvt + CVT_OFF.v[29];
    const float* cWu1  = cvt + CVT_OFF.v[30];
    const float* cbu1  = cvt + CVT_OFF.v[31];

    Ptrs ptrs;
    {
        int idx[32] = {0,1,4,5,6,7,8,9,10,11,12,13,14,15,16,17,18,19,20,21,
                       22,23,24,25,26,27,28,29,30,31,32,33};
        for(int i=0;i<32;i++) ptrs.p[i] = d_in[idx[i]];
    }

    k_detect<<<1,64,0,stream>>>((const unsigned short*)d_in[6], flag);
    {
        int maxv4 = (CVT_N[0] + 3)/4;            // atom is the largest tensor
        int gx = (maxv4 + 255)/256;
        k_cvt<<<dim3(gx,32),256,0,stream>>>(ptrs, cvt, flag);
    }

    k_embed<<<M_,256,0,stream>>>(cAtom, cWv, cbv, vf);
    k_sf0<<<B_,256,0,stream>>>(vf, cDm, sf);
    for(int d=0; d<D_; d++){
        k_super_pre<<<B_,256,0,stream>>>(d, sf, cWas, cbas, cWbmm,
                                         cWs2m, cbs2m, cWsup, cbsup, cWzm2, cbzm2,
                                         asw, s2m, ssf, stm2);
        k_gemm_big<<<dim3(M_/32,6),256,0,stream>>>(d, vf, cWam, cbam, cbbmm,
                                                   cWu2, cWu1, cbu1, asw, score,
                                                   proj_u2, proj_u1a);
        k_softmax<<<dim3(B_,K_),256,0,stream>>>(score, cDm, sumattn);
        k_t<<<dim3(B_,K_),256,0,stream>>>(score, vf, tbuf);
        k_m2s_sf<<<B_,256,0,stream>>>(d, tbuf, sumattn, cWm, cbm, cWm2s, cbm2s,
                                      cWzs1, cbzs1, cWzs2, cbzs2, ssf, sf);
        k_nei<<<M_,256,0,stream>>>(d, anb, bnb, cNbm, cBond, cWu2, cbu2, proj_u2, nei);
        k_mainself<<<M_/32,256,0,stream>>>(d, nei, cWu1, proj_u1a);
        k_update<<<M_/32,256,0,stream>>>(d, proj_u1a, cWzm1, cbzm1, stm2, s2m, vf);
    }
    k_out<<<(M_*H_+B_*H_+255)/256,256,0,stream>>>(vf, sf, d_out, flag);
}

// Round 5
// 964.279 us; speedup vs baseline: 1.4705x; 1.4705x over previous
//
#include <hip/hip_runtime.h>
#include <hip/hip_bf16.h>

#define B_ 32
#define N_ 512
#define NB_ 10
#define E_ 1024
#define H_ 256
#define A_ 82
#define K_ 4
#define D_ 3
#define M_ (B_*N_)   // 16384 rows

typedef unsigned short u16;
typedef __attribute__((ext_vector_type(8))) short bf16x8;
typedef __attribute__((ext_vector_type(4))) float f32x4;

__device__ __forceinline__ float b2f(u16 u){
    unsigned int x = ((unsigned int)u) << 16;
    return __builtin_bit_cast(float, x);
}
__device__ __forceinline__ u16 f2b(float f){
    unsigned int x = __builtin_bit_cast(unsigned int, f);
    unsigned int lsb = (x >> 16) & 1u;
    x += 0x7fffu + lsb;
    return (u16)(x >> 16);
}
__device__ __forceinline__ float sigmoidf_(float x){ return 1.f/(1.f+expf(-x)); }

// ---- conversion table: 32 float tensors (all inputs except int anb/bnb) ----
static constexpr int CVT_N[32] = {
    B_*N_*A_, B_*E_*6, B_*N_*NB_, B_*N_,
    A_*H_, H_,
    D_*K_*H_*H_, D_*K_*H_, D_*K_*H_*H_, D_*K_*H_,
    D_*K_*H_*H_, D_*K_*H_, D_*K_*H_, D_*K_,
    D_*K_*H_*H_, D_*H_, D_*H_*H_, D_*H_,
    D_*H_*H_, D_*H_, D_*H_*H_, D_*H_,
    D_*H_*H_, D_*H_, D_*H_*H_, D_*H_,
    D_*H_*H_, D_*H_, D_*(H_+6)*H_, D_*H_,
    D_*2*H_*H_, D_*H_
};
struct Offs { long v[33]; };
static constexpr Offs mk_offs(){
    Offs o{}; o.v[0]=0;
    for(int i=0;i<32;i++) o.v[i+1]=o.v[i]+CVT_N[i];
    return o;
}
static constexpr Offs CVT_OFF = mk_offs();

struct Ptrs { const void* p[32]; };

// ---------------- dtype detection: bf16 vs f32 ----------------
__global__ void k_detect(const unsigned short* __restrict__ wv_raw, int* __restrict__ flag){
    float v = b2f(wv_raw[threadIdx.x]);
    bool plaus = (v==v) && (fabsf(v) < 100.0f);
    unsigned long long m = __ballot(plaus);
    if (threadIdx.x==0) *flag = (m == ~0ULL) ? 1 : 0;
}

// ---------------- convert all float inputs to fp32 workspace ----------------
__global__ void k_cvt(Ptrs ptrs, float* __restrict__ dst, const int* __restrict__ flag){
    int t = blockIdx.y;
    int n = CVT_N[t];
    int i4 = blockIdx.x*256 + threadIdx.x;
    if (i4*4 >= n) return;
    const void* src = ptrs.p[t];
    float4 o;
    if (*flag){
        ushort4 u = ((const ushort4*)src)[i4];
        o.x=b2f(u.x); o.y=b2f(u.y); o.z=b2f(u.z); o.w=b2f(u.w);
    } else {
        o = ((const float4*)src)[i4];
    }
    *(float4*)(dst + CVT_OFF.v[t] + (size_t)i4*4) = o;
}

// ---------------- vertex embedding ----------------
__global__ void k_embed(const float* __restrict__ atom, const float* __restrict__ Wv,
                        const float* __restrict__ bv, float* __restrict__ vf){
    __shared__ float arow[A_];
    int row = blockIdx.x; int j = threadIdx.x;
    if (j < A_) arow[j] = atom[(size_t)row*A_ + j];
    __syncthreads();
    float acc = bv[j];
    for(int a=0;a<A_;a++) acc += arow[a]*Wv[a*H_ + j];
    vf[(size_t)row*H_ + j] = acc > 0.f ? acc : 0.01f*acc;
}

// ---------------- sf0 ----------------
__global__ void k_sf0(const float* __restrict__ vf, const float* __restrict__ dmask,
                      float* __restrict__ sf){
    int b = blockIdx.x, h = threadIdx.x;
    __shared__ float mk[N_];
    for(int n=threadIdx.x;n<N_;n+=256) mk[n] = dmask[b*N_+n];
    __syncthreads();
    float s=0.f;
    for(int n=0;n<N_;n++) s += mk[n]*vf[((size_t)b*N_+n)*H_ + h];
    sf[b*H_+h]=s;
}

// ---------------- super-side precompute ----------------
__global__ void k_super_pre(int d, const float* __restrict__ sf,
    const float* __restrict__ Wa_super, const float* __restrict__ ba_super,
    const float* __restrict__ Wbmm,
    const float* __restrict__ Ws2m, const float* __restrict__ bs2m,
    const float* __restrict__ Wsup, const float* __restrict__ bsup,
    const float* __restrict__ Wzm2, const float* __restrict__ bzm2,
    float* __restrict__ asw, float* __restrict__ s2m, float* __restrict__ ssf,
    float* __restrict__ stm2)
{
    int b = blockIdx.x, j = threadIdx.x;
    __shared__ float sfl[H_], s2ml[H_];
    sfl[j] = sf[b*H_+j];
    __syncthreads();
    for(int k=0;k<K_;k++){
        const float* W = Wa_super + ((size_t)(d*K_+k))*H_*H_;
        float acc = ba_super[(d*K_+k)*H_ + j];
        for(int h=0;h<H_;h++) acc += sfl[h]*W[h*H_+j];
        asw[(b*K_+k)*H_+j] = tanhf(acc)*Wbmm[(d*K_+k)*H_+j];
    }
    {
        const float* W = Ws2m + (size_t)d*H_*H_;
        float acc = bs2m[d*H_+j];
        for(int h=0;h<H_;h++) acc += sfl[h]*W[h*H_+j];
        float v = tanhf(acc); s2m[b*H_+j]=v; s2ml[j]=v;
    }
    {
        const float* W = Wsup + (size_t)d*H_*H_;
        float acc = bsup[d*H_+j];
        for(int h=0;h<H_;h++) acc += sfl[h]*W[h*H_+j];
        ssf[b*H_+j] = tanhf(acc);
    }
    __syncthreads();
    {
        const float* W = Wzm2 + (size_t)d*H_*H_;
        float acc = bzm2[d*H_+j];
        for(int h=0;h<H_;h++) acc += s2ml[h]*W[h*H_+j];
        stm2[b*H_+j]=acc;
    }
}

// ================= MFMA core from f32 inputs =================
// C[64x256] = A[64x256 f32] @ W[256x256 f32] ; staging converts f32->bf16 in LDS.
// 4 waves 2x2: wave(wy,wx) rows [wy*32,+32) cols [wx*128,+128)
// D map: col=lane&15, row=quad*4+reg ; A frag A[m=l15][k=quad*8+j] ; B frag B[k=quad*8+j][n=l15]
__device__ __forceinline__ void mfma_core_f32(const float* __restrict__ A,
    const float* __restrict__ W, f32x4 acc[2][8],
    u16* __restrict__ Als, u16* __restrict__ Ws)
{
    const int LSA = 40, LSW = 40;
    int tid = threadIdx.x;
    int lane = tid & 63, wave = tid >> 6;
    int wy = wave >> 1, wx = wave & 1;
    int quad = lane >> 4, l15 = lane & 15;
    #pragma unroll
    for(int mt=0;mt<2;mt++)
        #pragma unroll
        for(int nt=0;nt<8;nt++) acc[mt][nt] = (f32x4){0.f,0.f,0.f,0.f};
    int arow = tid >> 2;        // 0..63
    int ak8  = (tid & 3) * 8;   // 0,8,16,24
    for(int k0=0;k0<H_;k0+=32){
        // stage A: row arow, k in [k0+ak8, +8)
        float4 a0 = *(const float4*)(A + (size_t)arow*H_ + k0 + ak8);
        float4 a1 = *(const float4*)(A + (size_t)arow*H_ + k0 + ak8 + 4);
        union { u16 u[8]; bf16x8 v; } ua;
        ua.u[0]=f2b(a0.x); ua.u[1]=f2b(a0.y); ua.u[2]=f2b(a0.z); ua.u[3]=f2b(a0.w);
        ua.u[4]=f2b(a1.x); ua.u[5]=f2b(a1.y); ua.u[6]=f2b(a1.z); ua.u[7]=f2b(a1.w);
        *(bf16x8*)(Als + arow*LSA + ak8) = ua.v;
        // stage W column n=tid, all 32 k's (on-the-fly transpose)
        union { u16 u[32]; bf16x8 v[4]; } uw;
        #pragma unroll
        for(int r=0;r<32;r++) uw.u[r] = f2b(W[(size_t)(k0+r)*H_ + tid]);
        #pragma unroll
        for(int c=0;c<4;c++) *(bf16x8*)(Ws + tid*LSW + c*8) = uw.v[c];
        __syncthreads();
        bf16x8 af[2], bfr[8];
        #pragma unroll
        for(int mt=0;mt<2;mt++)
            af[mt] = *(const bf16x8*)(Als + (wy*32+mt*16+l15)*LSA + quad*8);
        #pragma unroll
        for(int nt=0;nt<8;nt++)
            bfr[nt] = *(const bf16x8*)(Ws + (wx*128+nt*16+l15)*LSW + quad*8);
        #pragma unroll
        for(int mt=0;mt<2;mt++)
            #pragma unroll
            for(int nt=0;nt<8;nt++)
                acc[mt][nt] = __builtin_amdgcn_mfma_f32_16x16x32_bf16(
                    af[mt], bfr[nt], acc[mt][nt], 0,0,0);
        __syncthreads();
    }
}

// ================= big GEMM over vf =================
// seg 0..3: fused attention score (tanh,*asw,row-reduce via LDS table)
// seg 4: proj_u2 (f32) ; seg 5: pu1a = acc + bu1 (f32)
__global__ __launch_bounds__(256) void k_gemm_big(int d, const float* __restrict__ vf,
    const float* __restrict__ Wa_main, const float* __restrict__ ba_main,
    const float* __restrict__ bbmm,
    const float* __restrict__ Wu2, const float* __restrict__ Wu1,
    const float* __restrict__ bu1,
    const float* __restrict__ asw, float* __restrict__ score,
    float* __restrict__ proj_u2, float* __restrict__ pu1a)
{
    __shared__ u16 Als[64*40];
    __shared__ u16 Ws[256*40];
    __shared__ float sred[64][33];
    int m0 = blockIdx.x*64;
    int seg = blockIdx.y;
    int b = m0 >> 9;
    const float* W;
    if (seg < 4)      W = Wa_main + ((size_t)(d*K_+seg))*H_*H_;
    else if (seg==4)  W = Wu2 + (size_t)d*(H_+6)*H_;
    else              W = Wu1 + (size_t)d*2*H_*H_;
    f32x4 acc[2][8];
    mfma_core_f32(vf + (size_t)m0*H_, W, acc, Als, Ws);
    int tid=threadIdx.x, lane=tid&63, wave=tid>>6;
    int wy=wave>>1, wx=wave&1, quad=lane>>4, l15=lane&15;
    if (seg < 4){
        const float* aswp = asw + (size_t)(b*K_+seg)*H_;
        const float* bap  = ba_main + (size_t)(d*K_+seg)*H_;
        float bbv[8], awv[8];
        #pragma unroll
        for(int nt=0;nt<8;nt++){
            int col = wx*128+nt*16+l15;
            bbv[nt]=bap[col]; awv[nt]=aswp[col];
        }
        #pragma unroll
        for(int mt=0;mt<2;mt++)
            #pragma unroll
            for(int r=0;r<4;r++){
                float p=0.f;
                #pragma unroll
                for(int nt=0;nt<8;nt++)
                    p += tanhf(acc[mt][nt][r]+bbv[nt])*awv[nt];
                int row = wy*32+mt*16+quad*4+r;
                sred[row][wx*16+l15] = p;
            }
        __syncthreads();
        if (tid < 64){
            float s=0.f;
            #pragma unroll 8
            for(int i=0;i<32;i++) s += sred[tid][i];
            score[(size_t)(b*K_+seg)*N_ + (m0&511) + tid] = s + bbmm[d*K_+seg];
        }
    } else if (seg==4){
        #pragma unroll
        for(int mt=0;mt<2;mt++)
            #pragma unroll
            for(int nt=0;nt<8;nt++){
                int col = wx*128+nt*16+l15;
                #pragma unroll
                for(int r=0;r<4;r++){
                    int row = m0 + wy*32+mt*16+quad*4+r;
                    proj_u2[(size_t)row*H_+col] = acc[mt][nt][r];
                }
            }
    } else {
        const float* bp = bu1 + d*H_;
        #pragma unroll
        for(int mt=0;mt<2;mt++)
            #pragma unroll
            for(int nt=0;nt<8;nt++){
                int col = wx*128+nt*16+l15;
                float bb = bp[col];
                #pragma unroll
                for(int r=0;r<4;r++){
                    int row = m0 + wy*32+mt*16+quad*4+r;
                    pu1a[(size_t)row*H_+col] = acc[mt][nt][r] + bb;
                }
            }
    }
}

// ===== main_self = lrelu(nei @ Wu1[H:] + pu, 0.1), in-place over pu =====
__global__ __launch_bounds__(256) void k_mainself(int d, const float* __restrict__ nei,
    const float* __restrict__ Wu1, float* __restrict__ pu)
{
    __shared__ u16 Als[64*40];
    __shared__ u16 Ws[256*40];
    int m0 = blockIdx.x*64;
    const float* W = Wu1 + (size_t)d*2*H_*H_ + (size_t)H_*H_;
    f32x4 acc[2][8];
    mfma_core_f32(nei + (size_t)m0*H_, W, acc, Als, Ws);
    int tid=threadIdx.x, lane=tid&63, wave=tid>>6;
    int wy=wave>>1, wx=wave&1, quad=lane>>4, l15=lane&15;
    #pragma unroll
    for(int mt=0;mt<2;mt++)
        #pragma unroll
        for(int nt=0;nt<8;nt++){
            int col = wx*128+nt*16+l15;
            #pragma unroll
            for(int r=0;r<4;r++){
                int row = m0 + wy*32+mt*16+quad*4+r;
                float v = acc[mt][nt][r] + pu[(size_t)row*H_+col];
                v = v>0.f? v : 0.1f*v;
                pu[(size_t)row*H_+col] = v;
            }
        }
}

// ===== z_main GEMM + GRU vf update =====
__global__ __launch_bounds__(256) void k_update(int d, const float* __restrict__ main_self,
    const float* __restrict__ Wzm1, const float* __restrict__ bzm1,
    const float* __restrict__ stm2, const float* __restrict__ s2m, float* __restrict__ vf)
{
    __shared__ u16 Als[64*40];
    __shared__ u16 Ws[256*40];
    int m0 = blockIdx.x*64; int b = m0>>9;
    f32x4 acc[2][8];
    mfma_core_f32(main_self + (size_t)m0*H_, Wzm1 + (size_t)d*H_*H_, acc, Als, Ws);
    int tid=threadIdx.x, lane=tid&63, wave=tid>>6;
    int wy=wave>>1, wx=wave&1, quad=lane>>4, l15=lane&15;
    #pragma unroll
    for(int mt=0;mt<2;mt++)
        #pragma unroll
        for(int nt=0;nt<8;nt++){
            int col = wx*128+nt*16+l15;
            float bz = bzm1[d*H_+col];
            float st = stm2[b*H_+col];
            float sm = s2m[b*H_+col];
            #pragma unroll
            for(int r=0;r<4;r++){
                int row = m0 + wy*32+mt*16+quad*4+r;
                float z = sigmoidf_(acc[mt][nt][r] + bz + st);
                float ms = main_self[(size_t)row*H_+col];
                vf[(size_t)row*H_+col] = (1.f-z)*ms + z*sm;
            }
        }
}

// ---------------- masked softmax ----------------
__global__ void k_softmax(float* __restrict__ score, const float* __restrict__ dmask,
                          float* __restrict__ sumattn){
    int b = blockIdx.x, k = blockIdx.y;
    int tid = threadIdx.x;
    __shared__ float sh[256];
    float* a = score + (size_t)(b*K_+k)*N_;
    float v0 = a[tid], v1 = a[tid+256];
    sh[tid]=fmaxf(v0,v1); __syncthreads();
    for(int s=128;s>0;s>>=1){ if(tid<s) sh[tid]=fmaxf(sh[tid],sh[tid+s]); __syncthreads(); }
    float m = sh[0]; __syncthreads();
    float e0 = expf(v0-m)*dmask[b*N_+tid], e1 = expf(v1-m)*dmask[b*N_+tid+256];
    sh[tid]=e0+e1; __syncthreads();
    for(int s=128;s>0;s>>=1){ if(tid<s) sh[tid]+=sh[tid+s]; __syncthreads(); }
    float S = sh[0];
    float inv = 1.f/(S+1e-6f);
    a[tid]=e0*inv; a[tid+256]=e1*inv;
    if(tid==0) sumattn[b*K_+k]=S*inv;
}

// ---------------- t[b,k,:] = attn[b,k,:] @ vf[b] ----------------
__global__ void k_t(const float* __restrict__ attn, const float* __restrict__ vf,
                    float* __restrict__ tbuf){
    int b=blockIdx.x, k=blockIdx.y, h=threadIdx.x;
    __shared__ float at[N_];
    for(int n=h;n<N_;n+=256) at[n]=attn[(size_t)(b*K_+k)*N_+n];
    __syncthreads();
    float acc=0.f;
    for(int n=0;n<N_;n++) acc += at[n]*vf[((size_t)b*N_+n)*H_+h];
    tbuf[(b*K_+k)*H_+h]=acc;
}

// ---------------- m2s -> main_to_super -> sf GRU update ----------------
__global__ void k_m2s_sf(int d, const float* __restrict__ tbuf, const float* __restrict__ sumattn,
    const float* __restrict__ Wm, const float* __restrict__ bm,
    const float* __restrict__ Wm2s, const float* __restrict__ bm2s,
    const float* __restrict__ Wzs1, const float* __restrict__ bzs1,
    const float* __restrict__ Wzs2, const float* __restrict__ bzs2,
    const float* __restrict__ ssf, float* __restrict__ sf)
{
    int b=blockIdx.x, j=threadIdx.x;
    __shared__ float m2sl[K_][H_];
    __shared__ float mtsl[H_];
    __shared__ float ssl[H_];
    ssl[j]=ssf[b*H_+j];
    for(int k=0;k<K_;k++){
        const float* W = Wm + ((size_t)(d*K_+k))*H_*H_;
        float acc = sumattn[b*K_+k]*bm[(d*K_+k)*H_+j];
        const float* t = tbuf + (b*K_+k)*H_;
        for(int h=0;h<H_;h++) acc += t[h]*W[h*H_+j];
        m2sl[k][j]=acc;
    }
    __syncthreads();
    {
        const float* W = Wm2s + (size_t)d*(K_*H_)*H_;
        const float* m2f = &m2sl[0][0];
        float acc = bm2s[d*H_+j];
        for(int kh=0;kh<K_*H_;kh++) acc += m2f[kh]*W[(size_t)kh*H_+j];
        mtsl[j]=tanhf(acc);
    }
    __syncthreads();
    {
        const float* W1 = Wzs1 + (size_t)d*H_*H_;
        const float* W2 = Wzs2 + (size_t)d*H_*H_;
        float acc = bzs1[d*H_+j] + bzs2[d*H_+j];
        for(int h=0;h<H_;h++) acc += ssl[h]*W1[h*H_+j] + mtsl[h]*W2[h*H_+j];
        float z = sigmoidf_(acc);
        sf[b*H_+j] = (1.f-z)*ssl[j] + z*mtsl[j];
    }
}

// ---- nei = sum_j mask * lrelu(proj_u2[anb] + bond@Wu2[H:] + bu2, 0.1) ----
__global__ void k_nei(int d, const int* __restrict__ anb, const int* __restrict__ bnb,
    const float* __restrict__ nbm, const float* __restrict__ bond,
    const float* __restrict__ Wu2, const float* __restrict__ bu2,
    const float* __restrict__ proj_u2, float* __restrict__ nei)
{
    __shared__ float W2s[6][256];
    __shared__ float bfeat[NB_][6];
    __shared__ int ai[NB_]; __shared__ int bi[NB_]; __shared__ float mk[NB_];
    int row = blockIdx.x; int b = row >> 9; int h = threadIdx.x;
    const float* W2 = Wu2 + (size_t)d*(H_+6)*H_ + (size_t)H_*H_;
    for(int i=h;i<6*H_;i+=256) W2s[i>>8][i&255] = W2[i];
    if (h<NB_){ ai[h]=anb[row*NB_+h]; bi[h]=bnb[row*NB_+h]; mk[h]=nbm[row*NB_+h]; }
    __syncthreads();
    if (h<NB_*6){ int jn=h/6, i=h-jn*6; bfeat[jn][i]=bond[((size_t)b*E_+bi[jn])*6+i]; }
    __syncthreads();
    float bu = bu2[d*H_+h];
    float acc=0.f;
    #pragma unroll
    for(int jn=0;jn<NB_;jn++){
        float v = proj_u2[((size_t)b*N_+ai[jn])*H_+h] + bu;
        #pragma unroll
        for(int i=0;i<6;i++) v += bfeat[jn][i]*W2s[i][h];
        v = v>0.f? v : 0.1f*v;
        acc += mk[jn]*v;
    }
    nei[(size_t)row*H_+h]=acc;
}

// ---------------- final output: [vf | sf], dtype per flag ----------------
__global__ void k_out(const float* __restrict__ vf, const float* __restrict__ sf,
                      void* __restrict__ out, const int* __restrict__ flag){
    int idx = blockIdx.x*256 + threadIdx.x;
    const int total = M_*H_ + B_*H_;
    if (idx >= total) return;
    float v = (idx < M_*H_) ? vf[idx] : sf[idx - M_*H_];
    if (*flag) ((unsigned short*)out)[idx] = f2b(v);
    else       ((float*)out)[idx] = v;
}

extern "C" void kernel_launch(void* const* d_in, const int* in_sizes, int n_in,
                              void* d_out, int out_size, void* d_ws, size_t ws_size,
                              hipStream_t stream)
{
    const int* anb = (const int*)d_in[2];
    const int* bnb = (const int*)d_in[3];

    // workspace layout (identical to round-2 pass)
    float* ws   = (float*)d_ws;
    int*   flag = (int*)ws;                 // 256 B reserved
    float* cvt  = ws + 64;
    float* p    = cvt + ((CVT_OFF.v[32] + 63) & ~63L);
    float* vf        = p; p += (size_t)M_*H_;
    float* proj_u2   = p; p += (size_t)M_*H_;
    float* proj_u1a  = p; p += (size_t)M_*H_;   // becomes main_self in-place
    float* nei       = p; p += (size_t)M_*H_;
    float* sf        = p; p += B_*H_;
    float* score     = p; p += B_*K_*N_;
    float* sumattn   = p; p += B_*K_;
    float* asw       = p; p += B_*K_*H_;
    float* s2m       = p; p += B_*H_;
    float* ssf       = p; p += B_*H_;
    float* stm2      = p; p += B_*H_;
    float* tbuf      = p; p += B_*K_*H_;

    const float* cAtom = cvt + CVT_OFF.v[0];
    const float* cBond = cvt + CVT_OFF.v[1];
    const float* cNbm  = cvt + CVT_OFF.v[2];
    const float* cDm   = cvt + CVT_OFF.v[3];
    const float* cWv   = cvt + CVT_OFF.v[4];
    const float* cbv   = cvt + CVT_OFF.v[5];
    const float* cWam  = cvt + CVT_OFF.v[6];
    const float* cbam  = cvt + CVT_OFF.v[7];
    const float* cWas  = cvt + CVT_OFF.v[8];
    const float* cbas  = cvt + CVT_OFF.v[9];
    const float* cWm   = cvt + CVT_OFF.v[10];
    const float* cbm   = cvt + CVT_OFF.v[11];
    const float* cWbmm = cvt + CVT_OFF.v[12];
    const float* cbbmm = cvt + CVT_OFF.v[13];
    const float* cWm2s = cvt + CVT_OFF.v[14];
    const float* cbm2s = cvt + CVT_OFF.v[15];
    const float* cWs2m = cvt + CVT_OFF.v[16];
    const float* cbs2m = cvt + CVT_OFF.v[17];
    const float* cWsup = cvt + CVT_OFF.v[18];
    const float* cbsup = cvt + CVT_OFF.v[19];
    const float* cWzm1 = cvt + CVT_OFF.v[20];
    const float* cbzm1 = cvt + CVT_OFF.v[21];
    const float* cWzm2 = cvt + CVT_OFF.v[22];
    const float* cbzm2 = cvt + CVT_OFF.v[23];
    const float* cWzs1 = cvt + CVT_OFF.v[24];
    const float* cbzs1 = cvt + CVT_OFF.v[25];
    const float* cWzs2 = cvt + CVT_OFF.v[26];
    const float* cbzs2 = cvt + CVT_OFF.v[27];
    const float* cWu2  = cvt + CVT_OFF.v[28];
    const float* cbu2  = cvt + CVT_OFF.v[29];
    const float* cWu1  = cvt + CVT_OFF.v[30];
    const float* cbu1  = cvt + CVT_OFF.v[31];

    Ptrs ptrs;
    {
        int idx[32] = {0,1,4,5,6,7,8,9,10,11,12,13,14,15,16,17,18,19,20,21,
                       22,23,24,25,26,27,28,29,30,31,32,33};
        for(int i=0;i<32;i++) ptrs.p[i] = d_in[idx[i]];
    }

    k_detect<<<1,64,0,stream>>>((const unsigned short*)d_in[6], flag);
    {
        int maxv4 = (CVT_N[0] + 3)/4;
        int gx = (maxv4 + 255)/256;
        k_cvt<<<dim3(gx,32),256,0,stream>>>(ptrs, cvt, flag);
    }

    k_embed<<<M_,256,0,stream>>>(cAtom, cWv, cbv, vf);
    k_sf0<<<B_,256,0,stream>>>(vf, cDm, sf);
    for(int d=0; d<D_; d++){
        k_super_pre<<<B_,256,0,stream>>>(d, sf, cWas, cbas, cWbmm,
                                         cWs2m, cbs2m, cWsup, cbsup, cWzm2, cbzm2,
                                         asw, s2m, ssf, stm2);
        k_gemm_big<<<dim3(M_/64,6),256,0,stream>>>(d, vf, cWam, cbam, cbbmm,
                                                   cWu2, cWu1, cbu1, asw, score,
                                                   proj_u2, proj_u1a);
        k_softmax<<<dim3(B_,K_),256,0,stream>>>(score, cDm, sumattn);
        k_t<<<dim3(B_,K_),256,0,stream>>>(score, vf, tbuf);
        k_m2s_sf<<<B_,256,0,stream>>>(d, tbuf, sumattn, cWm, cbm, cWm2s, cbm2s,
                                      cWzs1, cbzs1, cWzs2, cbzs2, ssf, sf);
        k_nei<<<M_,256,0,stream>>>(d, anb, bnb, cNbm, cBond, cWu2, cbu2, proj_u2, nei);
        k_mainself<<<M_/64,256,0,stream>>>(d, nei, cWu1, proj_u1a);
        k_update<<<M_/64,256,0,stream>>>(d, proj_u1a, cWzm1, cbzm1, stm2, s2m, vf);
    }
    k_out<<<(M_*H_+B_*H_+255)/256,256,0,stream>>>(vf, sf, d_out, flag);
}

// Round 6
// 802.720 us; speedup vs baseline: 1.7665x; 1.2013x over previous
//
#include <hip/hip_runtime.h>
#include <hip/hip_bf16.h>

#define B_ 32
#define N_ 512
#define NB_ 10
#define E_ 1024
#define H_ 256
#define A_ 82
#define K_ 4
#define D_ 3
#define M_ (B_*N_)   // 16384 rows

typedef unsigned short u16;
typedef __attribute__((ext_vector_type(8))) short bf16x8;
typedef __attribute__((ext_vector_type(4))) float f32x4;

__device__ __forceinline__ float b2f(u16 u){
    unsigned int x = ((unsigned int)u) << 16;
    return __builtin_bit_cast(float, x);
}
__device__ __forceinline__ u16 f2b(float f){
    unsigned int x = __builtin_bit_cast(unsigned int, f);
    unsigned int lsb = (x >> 16) & 1u;
    x += 0x7fffu + lsb;
    return (u16)(x >> 16);
}
__device__ __forceinline__ float sigmoidf_(float x){ return 1.f/(1.f+expf(-x)); }

// ---- conversion table: 31 float tensors (atom excluded, read raw; ints excluded) ----
// order: bond, nbmask, dmask, Wv, bv, Wa_main, ba_main, Wa_super, ba_super,
//        Wm, bm, Wbmm, bbmm, Wm2s, bm2s, Ws2m, bs2m, Wsup, bsup, Wzm1, bzm1,
//        Wzm2, bzm2, Wzs1, bzs1, Wzs2, bzs2, Wu2, bu2, Wu1, bu1
static constexpr int CVT_N[31] = {
    B_*E_*6, B_*N_*NB_, B_*N_,
    A_*H_, H_,
    D_*K_*H_*H_, D_*K_*H_, D_*K_*H_*H_, D_*K_*H_,
    D_*K_*H_*H_, D_*K_*H_, D_*K_*H_, D_*K_,
    D_*K_*H_*H_, D_*H_, D_*H_*H_, D_*H_,
    D_*H_*H_, D_*H_, D_*H_*H_, D_*H_,
    D_*H_*H_, D_*H_, D_*H_*H_, D_*H_,
    D_*H_*H_, D_*H_, D_*(H_+6)*H_, D_*H_,
    D_*2*H_*H_, D_*H_
};
struct Offs { long v[32]; };
static constexpr Offs mk_offs(){
    Offs o{}; o.v[0]=0;
    for(int i=0;i<31;i++) o.v[i+1]=o.v[i]+CVT_N[i];
    return o;
}
static constexpr Offs CVT_OFF = mk_offs();

struct Ptrs { const void* p[31]; };

// ---------------- dtype detection: bf16 vs f32 ----------------
__global__ void k_detect(const unsigned short* __restrict__ wv_raw, int* __restrict__ flag){
    float v = b2f(wv_raw[threadIdx.x]);
    bool plaus = (v==v) && (fabsf(v) < 100.0f);
    unsigned long long m = __ballot(plaus);
    if (threadIdx.x==0) *flag = (m == ~0ULL) ? 1 : 0;
}

// ---------------- convert float inputs to fp32 workspace ----------------
__global__ void k_cvt(Ptrs ptrs, float* __restrict__ dst, const int* __restrict__ flag){
    int t = blockIdx.y;
    int n = CVT_N[t];
    int i4 = blockIdx.x*256 + threadIdx.x;
    if (i4*4 >= n) return;
    const void* src = ptrs.p[t];
    float4 o;
    if (*flag){
        ushort4 u = ((const ushort4*)src)[i4];
        o.x=b2f(u.x); o.y=b2f(u.y); o.z=b2f(u.z); o.w=b2f(u.w);
    } else {
        o = ((const float4*)src)[i4];
    }
    *(float4*)(dst + CVT_OFF.v[t] + (size_t)i4*4) = o;
}

// ---------------- vertex embedding (raw bf16 atom) ----------------
__global__ void k_embed(const u16* __restrict__ atom, const float* __restrict__ Wv,
                        const float* __restrict__ bv, float* __restrict__ vf,
                        const int* __restrict__ flag){
    __shared__ float arow[A_];
    int row = blockIdx.x; int j = threadIdx.x;
    if (j < A_){
        if (*flag) arow[j] = b2f(atom[(size_t)row*A_ + j]);
        else       arow[j] = ((const float*)atom)[(size_t)row*A_ + j];
    }
    __syncthreads();
    float acc = bv[j];
    for(int a=0;a<A_;a++) acc += arow[a]*Wv[a*H_ + j];
    vf[(size_t)row*H_ + j] = acc > 0.f ? acc : 0.01f*acc;
}

// ---------------- sf0 ----------------
__global__ void k_sf0(const float* __restrict__ vf, const float* __restrict__ dmask,
                      float* __restrict__ sf){
    int b = blockIdx.x, h = threadIdx.x;
    __shared__ float mk[N_];
    for(int n=threadIdx.x;n<N_;n+=256) mk[n] = dmask[b*N_+n];
    __syncthreads();
    float s=0.f;
    #pragma unroll 8
    for(int n=0;n<N_;n++) s += mk[n]*vf[((size_t)b*N_+n)*H_ + h];
    sf[b*H_+h]=s;
}

// ======== S1: batched GEMV from sf: asw(k=0..3), s2m(m=4), ssf(m=5) ========
__global__ void k_s1(int d, const float* __restrict__ sf,
    const float* __restrict__ Was, const float* __restrict__ bas,
    const float* __restrict__ Wbmm,
    const float* __restrict__ Ws2m, const float* __restrict__ bs2m,
    const float* __restrict__ Wsup, const float* __restrict__ bsup,
    float* __restrict__ asw, float* __restrict__ s2m, float* __restrict__ ssf)
{
    int b = blockIdx.x, m = blockIdx.y, j = threadIdx.x;
    __shared__ float sfl[H_];
    sfl[j] = sf[b*H_+j];
    __syncthreads();
    const float* W; float bias;
    if (m < 4){ W = Was + (size_t)(d*K_+m)*H_*H_; bias = bas[(d*K_+m)*H_+j]; }
    else if (m==4){ W = Ws2m + (size_t)d*H_*H_; bias = bs2m[d*H_+j]; }
    else { W = Wsup + (size_t)d*H_*H_; bias = bsup[d*H_+j]; }
    float acc = bias;
    #pragma unroll 8
    for(int h=0;h<H_;h++) acc += sfl[h]*W[h*H_+j];
    float v = tanhf(acc);
    if (m < 4) asw[(b*K_+m)*H_+j] = v * Wbmm[(d*K_+m)*H_+j];
    else if (m==4) s2m[b*H_+j] = v;
    else ssf[b*H_+j] = v;
}

// ======== S2: stm2 partials (h-split by 4): stm2p[c][b][j] ========
__global__ void k_s2(int d, const float* __restrict__ s2m,
    const float* __restrict__ Wzm2, const float* __restrict__ bzm2,
    float* __restrict__ stm2p)
{
    int b=blockIdx.x, c=blockIdx.y, j=threadIdx.x;
    __shared__ float xl[64];
    if (j<64) xl[j] = s2m[b*H_ + c*64 + j];
    __syncthreads();
    const float* W = Wzm2 + (size_t)d*H_*H_ + (size_t)(c*64)*H_;
    float acc = (c==0) ? bzm2[d*H_+j] : 0.f;
    #pragma unroll 8
    for(int h=0;h<64;h++) acc += xl[h]*W[h*H_+j];
    stm2p[((size_t)c*B_+b)*H_+j] = acc;
}

// ================= MFMA core from f32 inputs (proven in R5) =================
__device__ __forceinline__ void mfma_core_f32(const float* __restrict__ A,
    const float* __restrict__ W, f32x4 acc[2][8],
    u16* __restrict__ Als, u16* __restrict__ Ws)
{
    const int LSA = 40, LSW = 40;
    int tid = threadIdx.x;
    int lane = tid & 63, wave = tid >> 6;
    int wy = wave >> 1, wx = wave & 1;
    int quad = lane >> 4, l15 = lane & 15;
    #pragma unroll
    for(int mt=0;mt<2;mt++)
        #pragma unroll
        for(int nt=0;nt<8;nt++) acc[mt][nt] = (f32x4){0.f,0.f,0.f,0.f};
    int arow = tid >> 2;
    int ak8  = (tid & 3) * 8;
    for(int k0=0;k0<H_;k0+=32){
        float4 a0 = *(const float4*)(A + (size_t)arow*H_ + k0 + ak8);
        float4 a1 = *(const float4*)(A + (size_t)arow*H_ + k0 + ak8 + 4);
        union { u16 u[8]; bf16x8 v; } ua;
        ua.u[0]=f2b(a0.x); ua.u[1]=f2b(a0.y); ua.u[2]=f2b(a0.z); ua.u[3]=f2b(a0.w);
        ua.u[4]=f2b(a1.x); ua.u[5]=f2b(a1.y); ua.u[6]=f2b(a1.z); ua.u[7]=f2b(a1.w);
        *(bf16x8*)(Als + arow*LSA + ak8) = ua.v;
        union { u16 u[32]; bf16x8 v[4]; } uw;
        #pragma unroll
        for(int r=0;r<32;r++) uw.u[r] = f2b(W[(size_t)(k0+r)*H_ + tid]);
        #pragma unroll
        for(int c=0;c<4;c++) *(bf16x8*)(Ws + tid*LSW + c*8) = uw.v[c];
        __syncthreads();
        bf16x8 af[2], bfr[8];
        #pragma unroll
        for(int mt=0;mt<2;mt++)
            af[mt] = *(const bf16x8*)(Als + (wy*32+mt*16+l15)*LSA + quad*8);
        #pragma unroll
        for(int nt=0;nt<8;nt++)
            bfr[nt] = *(const bf16x8*)(Ws + (wx*128+nt*16+l15)*LSW + quad*8);
        #pragma unroll
        for(int mt=0;mt<2;mt++)
            #pragma unroll
            for(int nt=0;nt<8;nt++)
                acc[mt][nt] = __builtin_amdgcn_mfma_f32_16x16x32_bf16(
                    af[mt], bfr[nt], acc[mt][nt], 0,0,0);
        __syncthreads();
    }
}

// ================= big GEMM over vf =================
__global__ __launch_bounds__(256) void k_gemm_big(int d, const float* __restrict__ vf,
    const float* __restrict__ Wa_main, const float* __restrict__ ba_main,
    const float* __restrict__ bbmm,
    const float* __restrict__ Wu2, const float* __restrict__ Wu1,
    const float* __restrict__ bu1,
    const float* __restrict__ asw, float* __restrict__ score,
    float* __restrict__ proj_u2, float* __restrict__ pu1a)
{
    __shared__ u16 Als[64*40];
    __shared__ u16 Ws[256*40];
    __shared__ float sred[64][33];
    int m0 = blockIdx.x*64;
    int seg = blockIdx.y;
    int b = m0 >> 9;
    const float* W;
    if (seg < 4)      W = Wa_main + ((size_t)(d*K_+seg))*H_*H_;
    else if (seg==4)  W = Wu2 + (size_t)d*(H_+6)*H_;
    else              W = Wu1 + (size_t)d*2*H_*H_;
    f32x4 acc[2][8];
    mfma_core_f32(vf + (size_t)m0*H_, W, acc, Als, Ws);
    int tid=threadIdx.x, lane=tid&63, wave=tid>>6;
    int wy=wave>>1, wx=wave&1, quad=lane>>4, l15=lane&15;
    if (seg < 4){
        const float* aswp = asw + (size_t)(b*K_+seg)*H_;
        const float* bap  = ba_main + (size_t)(d*K_+seg)*H_;
        float bbv[8], awv[8];
        #pragma unroll
        for(int nt=0;nt<8;nt++){
            int col = wx*128+nt*16+l15;
            bbv[nt]=bap[col]; awv[nt]=aswp[col];
        }
        #pragma unroll
        for(int mt=0;mt<2;mt++)
            #pragma unroll
            for(int r=0;r<4;r++){
                float p=0.f;
                #pragma unroll
                for(int nt=0;nt<8;nt++)
                    p += tanhf(acc[mt][nt][r]+bbv[nt])*awv[nt];
                int row = wy*32+mt*16+quad*4+r;
                sred[row][wx*16+l15] = p;
            }
        __syncthreads();
        if (tid < 64){
            float s=0.f;
            #pragma unroll 8
            for(int i=0;i<32;i++) s += sred[tid][i];
            score[(size_t)(b*K_+seg)*N_ + (m0&511) + tid] = s + bbmm[d*K_+seg];
        }
    } else if (seg==4){
        #pragma unroll
        for(int mt=0;mt<2;mt++)
            #pragma unroll
            for(int nt=0;nt<8;nt++){
                int col = wx*128+nt*16+l15;
                #pragma unroll
                for(int r=0;r<4;r++){
                    int row = m0 + wy*32+mt*16+quad*4+r;
                    proj_u2[(size_t)row*H_+col] = acc[mt][nt][r];
                }
            }
    } else {
        const float* bp = bu1 + d*H_;
        #pragma unroll
        for(int mt=0;mt<2;mt++)
            #pragma unroll
            for(int nt=0;nt<8;nt++){
                int col = wx*128+nt*16+l15;
                float bb = bp[col];
                #pragma unroll
                for(int r=0;r<4;r++){
                    int row = m0 + wy*32+mt*16+quad*4+r;
                    pu1a[(size_t)row*H_+col] = acc[mt][nt][r] + bb;
                }
            }
    }
}

// ===== main_self = lrelu(nei @ Wu1[H:] + pu, 0.1), in-place over pu =====
__global__ __launch_bounds__(256) void k_mainself(int d, const float* __restrict__ nei,
    const float* __restrict__ Wu1, float* __restrict__ pu)
{
    __shared__ u16 Als[64*40];
    __shared__ u16 Ws[256*40];
    int m0 = blockIdx.x*64;
    const float* W = Wu1 + (size_t)d*2*H_*H_ + (size_t)H_*H_;
    f32x4 acc[2][8];
    mfma_core_f32(nei + (size_t)m0*H_, W, acc, Als, Ws);
    int tid=threadIdx.x, lane=tid&63, wave=tid>>6;
    int wy=wave>>1, wx=wave&1, quad=lane>>4, l15=lane&15;
    #pragma unroll
    for(int mt=0;mt<2;mt++)
        #pragma unroll
        for(int nt=0;nt<8;nt++){
            int col = wx*128+nt*16+l15;
            #pragma unroll
            for(int r=0;r<4;r++){
                int row = m0 + wy*32+mt*16+quad*4+r;
                float v = acc[mt][nt][r] + pu[(size_t)row*H_+col];
                v = v>0.f? v : 0.1f*v;
                pu[(size_t)row*H_+col] = v;
            }
        }
}

// ===== z_main GEMM + GRU vf update (stm2 from 4 partials) =====
__global__ __launch_bounds__(256) void k_update(int d, const float* __restrict__ main_self,
    const float* __restrict__ Wzm1, const float* __restrict__ bzm1,
    const float* __restrict__ stm2p, const float* __restrict__ s2m, float* __restrict__ vf)
{
    __shared__ u16 Als[64*40];
    __shared__ u16 Ws[256*40];
    int m0 = blockIdx.x*64; int b = m0>>9;
    f32x4 acc[2][8];
    mfma_core_f32(main_self + (size_t)m0*H_, Wzm1 + (size_t)d*H_*H_, acc, Als, Ws);
    int tid=threadIdx.x, lane=tid&63, wave=tid>>6;
    int wy=wave>>1, wx=wave&1, quad=lane>>4, l15=lane&15;
    #pragma unroll
    for(int mt=0;mt<2;mt++)
        #pragma unroll
        for(int nt=0;nt<8;nt++){
            int col = wx*128+nt*16+l15;
            float bz = bzm1[d*H_+col];
            float st = stm2p[(size_t)(0*B_+b)*H_+col] + stm2p[(size_t)(1*B_+b)*H_+col]
                     + stm2p[(size_t)(2*B_+b)*H_+col] + stm2p[(size_t)(3*B_+b)*H_+col];
            float sm = s2m[b*H_+col];
            #pragma unroll
            for(int r=0;r<4;r++){
                int row = m0 + wy*32+mt*16+quad*4+r;
                float z = sigmoidf_(acc[mt][nt][r] + bz + st);
                float ms = main_self[(size_t)row*H_+col];
                vf[(size_t)row*H_+col] = (1.f-z)*ms + z*sm;
            }
        }
}

// ---------------- masked softmax ----------------
__global__ void k_softmax(float* __restrict__ score, const float* __restrict__ dmask,
                          float* __restrict__ sumattn){
    int b = blockIdx.x, k = blockIdx.y;
    int tid = threadIdx.x;
    __shared__ float sh[256];
    float* a = score + (size_t)(b*K_+k)*N_;
    float v0 = a[tid], v1 = a[tid+256];
    sh[tid]=fmaxf(v0,v1); __syncthreads();
    for(int s=128;s>0;s>>=1){ if(tid<s) sh[tid]=fmaxf(sh[tid],sh[tid+s]); __syncthreads(); }
    float m = sh[0]; __syncthreads();
    float e0 = expf(v0-m)*dmask[b*N_+tid], e1 = expf(v1-m)*dmask[b*N_+tid+256];
    sh[tid]=e0+e1; __syncthreads();
    for(int s=128;s>0;s>>=1){ if(tid<s) sh[tid]+=sh[tid+s]; __syncthreads(); }
    float S = sh[0];
    float inv = 1.f/(S+1e-6f);
    a[tid]=e0*inv; a[tid+256]=e1*inv;
    if(tid==0) sumattn[b*K_+k]=S*inv;
}

// ======== t partials: tpart[c][b][k][h] = sum_{n in chunk c} attn*vf ========
__global__ void k_t2(const float* __restrict__ attn, const float* __restrict__ vf,
                     float* __restrict__ tpart){
    int b=blockIdx.x, k=blockIdx.y, c=blockIdx.z, h=threadIdx.x;
    __shared__ float at[256];
    at[h] = attn[(size_t)(b*K_+k)*N_ + c*256 + h];
    __syncthreads();
    float acc=0.f;
    const float* vfp = vf + ((size_t)b*N_ + c*256)*H_ + h;
    #pragma unroll 8
    for(int n=0;n<256;n++) acc += at[n]*vfp[(size_t)n*H_];
    tpart[((size_t)(c*B_+b)*K_+k)*H_+h]=acc;
}

// ======== M1: m2s[b,k,j] = sumattn*bm + t @ Wm[k] ========
__global__ void k_m1(int d, const float* __restrict__ tpart, const float* __restrict__ sumattn,
    const float* __restrict__ Wm, const float* __restrict__ bm, float* __restrict__ m2s)
{
    int b=blockIdx.x, k=blockIdx.y, j=threadIdx.x;
    __shared__ float tl[H_];
    tl[j] = tpart[((size_t)(0*B_+b)*K_+k)*H_+j] + tpart[((size_t)(1*B_+b)*K_+k)*H_+j];
    __syncthreads();
    const float* W = Wm + (size_t)(d*K_+k)*H_*H_;
    float acc = sumattn[b*K_+k]*bm[(d*K_+k)*H_+j];
    #pragma unroll 8
    for(int h=0;h<H_;h++) acc += tl[h]*W[h*H_+j];
    m2s[(size_t)(b*K_+k)*H_+j]=acc;
}

// ======== M2: mts partials over kh-chunks (chunk c == head c) ========
__global__ void k_m2(int d, const float* __restrict__ m2s, const float* __restrict__ Wm2s,
                     float* __restrict__ mtsp)
{
    int b=blockIdx.x, c=blockIdx.y, j=threadIdx.x;
    __shared__ float xl[H_];
    xl[j]=m2s[(size_t)(b*K_+c)*H_+j];
    __syncthreads();
    const float* W = Wm2s + (size_t)d*(K_*H_)*H_ + (size_t)(c*H_)*H_;
    float acc=0.f;
    #pragma unroll 8
    for(int h=0;h<H_;h++) acc += xl[h]*W[h*H_+j];
    mtsp[((size_t)c*B_+b)*H_+j]=acc;
}

// ======== mts[b,j] = tanh(sum parts + bm2s) ========
__global__ void k_mts(int d, const float* __restrict__ mtsp, const float* __restrict__ bm2s,
                      float* __restrict__ mts){
    int b=blockIdx.x, j=threadIdx.x;
    float acc = bm2s[d*H_+j];
    #pragma unroll
    for(int c=0;c<4;c++) acc += mtsp[((size_t)c*B_+b)*H_+j];
    mts[b*H_+j]=tanhf(acc);
}

// ======== M3: p1 = ssf@Wzs1 (m=0), p2 = mts@Wzs2 (m=1) ========
__global__ void k_m3(int d, const float* __restrict__ ssf, const float* __restrict__ mts,
    const float* __restrict__ Wzs1, const float* __restrict__ Wzs2,
    float* __restrict__ p1, float* __restrict__ p2)
{
    int b=blockIdx.x, m=blockIdx.y, j=threadIdx.x;
    __shared__ float xl[H_];
    const float* x = m ? mts : ssf;
    xl[j]=x[b*H_+j];
    __syncthreads();
    const float* W = (m ? Wzs2 : Wzs1) + (size_t)d*H_*H_;
    float acc=0.f;
    #pragma unroll 8
    for(int h=0;h<H_;h++) acc += xl[h]*W[h*H_+j];
    (m ? p2 : p1)[b*H_+j]=acc;
}

// ======== sf GRU update ========
__global__ void k_sfup(int d, const float* __restrict__ p1, const float* __restrict__ p2,
    const float* __restrict__ bzs1, const float* __restrict__ bzs2,
    const float* __restrict__ ssf, const float* __restrict__ mts, float* __restrict__ sf)
{
    int b=blockIdx.x, j=threadIdx.x;
    float z = sigmoidf_(p1[b*H_+j]+bzs1[d*H_+j]+p2[b*H_+j]+bzs2[d*H_+j]);
    sf[b*H_+j]=(1.f-z)*ssf[b*H_+j]+z*mts[b*H_+j];
}

// ---- nei = sum_j mask * lrelu(proj_u2[anb] + bond@Wu2[H:] + bu2, 0.1) ----
__global__ void k_nei(int d, const int* __restrict__ anb, const int* __restrict__ bnb,
    const float* __restrict__ nbm, const float* __restrict__ bond,
    const float* __restrict__ Wu2, const float* __restrict__ bu2,
    const float* __restrict__ proj_u2, float* __restrict__ nei)
{
    __shared__ float W2s[6][256];
    __shared__ float bfeat[NB_][6];
    __shared__ int ai[NB_]; __shared__ int bi[NB_]; __shared__ float mk[NB_];
    int row = blockIdx.x; int b = row >> 9; int h = threadIdx.x;
    const float* W2 = Wu2 + (size_t)d*(H_+6)*H_ + (size_t)H_*H_;
    for(int i=h;i<6*H_;i+=256) W2s[i>>8][i&255] = W2[i];
    if (h<NB_){ ai[h]=anb[row*NB_+h]; bi[h]=bnb[row*NB_+h]; mk[h]=nbm[row*NB_+h]; }
    __syncthreads();
    if (h<NB_*6){ int jn=h/6, i=h-jn*6; bfeat[jn][i]=bond[((size_t)b*E_+bi[jn])*6+i]; }
    __syncthreads();
    float bu = bu2[d*H_+h];
    float acc=0.f;
    #pragma unroll
    for(int jn=0;jn<NB_;jn++){
        float v = proj_u2[((size_t)b*N_+ai[jn])*H_+h] + bu;
        #pragma unroll
        for(int i=0;i<6;i++) v += bfeat[jn][i]*W2s[i][h];
        v = v>0.f? v : 0.1f*v;
        acc += mk[jn]*v;
    }
    nei[(size_t)row*H_+h]=acc;
}

// ---------------- final output: [vf | sf], dtype per flag ----------------
__global__ void k_out(const float* __restrict__ vf, const float* __restrict__ sf,
                      void* __restrict__ out, const int* __restrict__ flag){
    int idx = blockIdx.x*256 + threadIdx.x;
    const int total = M_*H_ + B_*H_;
    if (idx >= total) return;
    float v = (idx < M_*H_) ? vf[idx] : sf[idx - M_*H_];
    if (*flag) ((unsigned short*)out)[idx] = f2b(v);
    else       ((float*)out)[idx] = v;
}

extern "C" void kernel_launch(void* const* d_in, const int* in_sizes, int n_in,
                              void* d_out, int out_size, void* d_ws, size_t ws_size,
                              hipStream_t stream)
{
    const int* anb = (const int*)d_in[2];
    const int* bnb = (const int*)d_in[3];

    float* ws   = (float*)d_ws;
    int*   flag = (int*)ws;                 // 256 B reserved
    float* cvt  = ws + 64;
    float* p    = cvt + ((CVT_OFF.v[31] + 63) & ~63L);
    float* vf        = p; p += (size_t)M_*H_;
    float* proj_u2   = p; p += (size_t)M_*H_;
    float* proj_u1a  = p; p += (size_t)M_*H_;   // becomes main_self in-place
    float* nei       = p; p += (size_t)M_*H_;
    float* sf        = p; p += B_*H_;
    float* score     = p; p += B_*K_*N_;
    float* sumattn   = p; p += B_*K_;
    float* asw       = p; p += B_*K_*H_;
    float* s2m       = p; p += B_*H_;
    float* ssf       = p; p += B_*H_;
    float* stm2p     = p; p += 4*B_*H_;
    float* tpart     = p; p += 2*B_*K_*H_;
    float* m2s       = p; p += B_*K_*H_;
    float* mtsp      = p; p += 4*B_*H_;
    float* mts       = p; p += B_*H_;
    float* p1        = p; p += B_*H_;
    float* p2        = p; p += B_*H_;

    const float* cBond = cvt + CVT_OFF.v[0];
    const float* cNbm  = cvt + CVT_OFF.v[1];
    const float* cDm   = cvt + CVT_OFF.v[2];
    const float* cWv   = cvt + CVT_OFF.v[3];
    const float* cbv   = cvt + CVT_OFF.v[4];
    const float* cWam  = cvt + CVT_OFF.v[5];
    const float* cbam  = cvt + CVT_OFF.v[6];
    const float* cWas  = cvt + CVT_OFF.v[7];
    const float* cbas  = cvt + CVT_OFF.v[8];
    const float* cWm   = cvt + CVT_OFF.v[9];
    const float* cbm   = cvt + CVT_OFF.v[10];
    const float* cWbmm = cvt + CVT_OFF.v[11];
    const float* cbbmm = cvt + CVT_OFF.v[12];
    const float* cWm2s = cvt + CVT_OFF.v[13];
    const float* cbm2s = cvt + CVT_OFF.v[14];
    const float* cWs2m = cvt + CVT_OFF.v[15];
    const float* cbs2m = cvt + CVT_OFF.v[16];
    const float* cWsup = cvt + CVT_OFF.v[17];
    const float* cbsup = cvt + CVT_OFF.v[18];
    const float* cWzm1 = cvt + CVT_OFF.v[19];
    const float* cbzm1 = cvt + CVT_OFF.v[20];
    const float* cWzm2 = cvt + CVT_OFF.v[21];
    const float* cbzm2 = cvt + CVT_OFF.v[22];
    const float* cWzs1 = cvt + CVT_OFF.v[23];
    const float* cbzs1 = cvt + CVT_OFF.v[24];
    const float* cWzs2 = cvt + CVT_OFF.v[25];
    const float* cbzs2 = cvt + CVT_OFF.v[26];
    const float* cWu2  = cvt + CVT_OFF.v[27];
    const float* cbu2  = cvt + CVT_OFF.v[28];
    const float* cWu1  = cvt + CVT_OFF.v[29];
    const float* cbu1  = cvt + CVT_OFF.v[30];

    Ptrs ptrs;
    {
        int idx[31] = {1,4,5,6,7,8,9,10,11,12,13,14,15,16,17,18,19,20,21,
                       22,23,24,25,26,27,28,29,30,31,32,33};
        for(int i=0;i<31;i++) ptrs.p[i] = d_in[idx[i]];
    }

    k_detect<<<1,64,0,stream>>>((const unsigned short*)d_in[6], flag);
    {
        int maxv4 = (D_*K_*H_*H_ + 3)/4;   // largest tensor: 786432 elems
        int gx = (maxv4 + 255)/256;
        k_cvt<<<dim3(gx,31),256,0,stream>>>(ptrs, cvt, flag);
    }

    k_embed<<<M_,256,0,stream>>>((const u16*)d_in[0], cWv, cbv, vf, flag);
    k_sf0<<<B_,256,0,stream>>>(vf, cDm, sf);
    for(int d=0; d<D_; d++){
        k_s1<<<dim3(B_,6),256,0,stream>>>(d, sf, cWas, cbas, cWbmm,
                                          cWs2m, cbs2m, cWsup, cbsup, asw, s2m, ssf);
        k_s2<<<dim3(B_,4),256,0,stream>>>(d, s2m, cWzm2, cbzm2, stm2p);
        k_gemm_big<<<dim3(M_/64,6),256,0,stream>>>(d, vf, cWam, cbam, cbbmm,
                                                   cWu2, cWu1, cbu1, asw, score,
                                                   proj_u2, proj_u1a);
        k_softmax<<<dim3(B_,K_),256,0,stream>>>(score, cDm, sumattn);
        k_t2<<<dim3(B_,K_,2),256,0,stream>>>(score, vf, tpart);
        k_m1<<<dim3(B_,K_),256,0,stream>>>(d, tpart, sumattn, cWm, cbm, m2s);
        k_m2<<<dim3(B_,4),256,0,stream>>>(d, m2s, cWm2s, mtsp);
        k_mts<<<B_,256,0,stream>>>(d, mtsp, cbm2s, mts);
        k_m3<<<dim3(B_,2),256,0,stream>>>(d, ssf, mts, cWzs1, cWzs2, p1, p2);
        k_sfup<<<B_,256,0,stream>>>(d, p1, p2, cbzs1, cbzs2, ssf, mts, sf);
        k_nei<<<M_,256,0,stream>>>(d, anb, bnb, cNbm, cBond, cWu2, cbu2, proj_u2, nei);
        k_mainself<<<M_/64,256,0,stream>>>(d, nei, cWu1, proj_u1a);
        k_update<<<M_/64,256,0,stream>>>(d, proj_u1a, cWzm1, cbzm1, stm2p, s2m, vf);
    }
    k_out<<<(M_*H_+B_*H_+255)/256,256,0,stream>>>(vf, sf, d_out, flag);
}

// Round 7
// 746.020 us; speedup vs baseline: 1.9007x; 1.0760x over previous
//
#include <hip/hip_runtime.h>
#include <hip/hip_bf16.h>

#define B_ 32
#define N_ 512
#define NB_ 10
#define E_ 1024
#define H_ 256
#define A_ 82
#define K_ 4
#define D_ 3
#define M_ (B_*N_)   // 16384 rows

typedef unsigned short u16;
typedef __attribute__((ext_vector_type(8))) short bf16x8;
typedef __attribute__((ext_vector_type(4))) float f32x4;

__device__ __forceinline__ float b2f(u16 u){
    unsigned int x = ((unsigned int)u) << 16;
    return __builtin_bit_cast(float, x);
}
__device__ __forceinline__ u16 f2b(float f){
    unsigned int x = __builtin_bit_cast(unsigned int, f);
    unsigned int lsb = (x >> 16) & 1u;
    x += 0x7fffu + lsb;
    return (u16)(x >> 16);
}
__device__ __forceinline__ float sigmoidf_(float x){ return 1.f/(1.f+expf(-x)); }

// ---- conversion table: 31 float tensors (atom excluded; ints excluded) ----
static constexpr int CVT_N[31] = {
    B_*E_*6, B_*N_*NB_, B_*N_,
    A_*H_, H_,
    D_*K_*H_*H_, D_*K_*H_, D_*K_*H_*H_, D_*K_*H_,
    D_*K_*H_*H_, D_*K_*H_, D_*K_*H_, D_*K_,
    D_*K_*H_*H_, D_*H_, D_*H_*H_, D_*H_,
    D_*H_*H_, D_*H_, D_*H_*H_, D_*H_,
    D_*H_*H_, D_*H_, D_*H_*H_, D_*H_,
    D_*H_*H_, D_*H_, D_*(H_+6)*H_, D_*H_,
    D_*2*H_*H_, D_*H_
};
struct Offs { long v[32]; };
static constexpr Offs mk_offs(){
    Offs o{}; o.v[0]=0;
    for(int i=0;i<31;i++) o.v[i+1]=o.v[i]+CVT_N[i];
    return o;
}
static constexpr Offs CVT_OFF = mk_offs();

struct Ptrs { const void* p[31]; };

// ---------------- dtype detection: bf16 vs f32 ----------------
__global__ void k_detect(const unsigned short* __restrict__ wv_raw, int* __restrict__ flag){
    float v = b2f(wv_raw[threadIdx.x]);
    bool plaus = (v==v) && (fabsf(v) < 100.0f);
    unsigned long long m = __ballot(plaus);
    if (threadIdx.x==0) *flag = (m == ~0ULL) ? 1 : 0;
}

// ---------------- convert float inputs to fp32 workspace ----------------
__global__ void k_cvt(Ptrs ptrs, float* __restrict__ dst, const int* __restrict__ flag){
    int t = blockIdx.y;
    int n = CVT_N[t];
    int i4 = blockIdx.x*256 + threadIdx.x;
    if (i4*4 >= n) return;
    const void* src = ptrs.p[t];
    float4 o;
    if (*flag){
        ushort4 u = ((const ushort4*)src)[i4];
        o.x=b2f(u.x); o.y=b2f(u.y); o.z=b2f(u.z); o.w=b2f(u.w);
    } else {
        o = ((const float4*)src)[i4];
    }
    *(float4*)(dst + CVT_OFF.v[t] + (size_t)i4*4) = o;
}

// ======== WT precompute: 24 H×H matrices -> bf16, tiled [mi][k0/32][n][32] ========
// [0..11]=Wa_main(d,k), [12..14]=Wu2[:H], [15..17]=Wu1[:H], [18..20]=Wu1[H:2H], [21..23]=Wzm1
__global__ void k_wt(const float* __restrict__ Wam, const float* __restrict__ Wu2,
                     const float* __restrict__ Wu1, const float* __restrict__ Wzm1,
                     u16* __restrict__ WT){
    int mi = blockIdx.z;
    const float* src;
    if (mi<12)      src = Wam  + (size_t)mi*H_*H_;
    else if (mi<15) src = Wu2  + (size_t)(mi-12)*(H_+6)*H_;
    else if (mi<18) src = Wu1  + (size_t)(mi-15)*2*H_*H_;
    else if (mi<21) src = Wu1  + (size_t)(mi-18)*2*H_*H_ + (size_t)H_*H_;
    else            src = Wzm1 + (size_t)(mi-21)*H_*H_;
    __shared__ float t[32][33];
    int x = threadIdx.x, y = threadIdx.y;
    int k0 = blockIdx.y*32, n0 = blockIdx.x*32;
    for(int yy=y; yy<32; yy+=8) t[yy][x] = src[(size_t)(k0+yy)*H_ + n0+x];
    __syncthreads();
    u16* dst = WT + ((size_t)mi*8 + (k0>>5))*(256*32);
    // dst[n][kk] = src[k0+kk][n]; here n=n0+yy, kk=x, value t[x][yy]=src[k0+x][n0+yy]
    for(int yy=y; yy<32; yy+=8) dst[(size_t)(n0+yy)*32 + x] = f2b(t[x][yy]);
}

// ---------------- vertex embedding: 8 rows per block ----------------
__global__ void k_embed(const u16* __restrict__ atom, const float* __restrict__ Wv,
                        const float* __restrict__ bv, float* __restrict__ vf,
                        const int* __restrict__ flag){
    __shared__ float arow[8][A_];
    int r0 = blockIdx.x*8; int j = threadIdx.x;
    int fl = *flag;
    for(int i=j;i<8*A_;i+=256){
        int r=i/A_, a=i-r*A_;
        arow[r][a] = fl ? b2f(atom[(size_t)(r0+r)*A_+a])
                        : ((const float*)atom)[(size_t)(r0+r)*A_+a];
    }
    __syncthreads();
    float acc[8];
    float bj = bv[j];
    #pragma unroll
    for(int r=0;r<8;r++) acc[r]=bj;
    for(int a=0;a<A_;a++){
        float w = Wv[a*H_+j];
        #pragma unroll
        for(int r=0;r<8;r++) acc[r] += arow[r][a]*w;
    }
    #pragma unroll
    for(int r=0;r<8;r++){
        float v = acc[r];
        vf[(size_t)(r0+r)*H_+j] = v>0.f ? v : 0.01f*v;
    }
}

// ---------------- sf0 ----------------
__global__ void k_sf0(const float* __restrict__ vf, const float* __restrict__ dmask,
                      float* __restrict__ sf){
    int b = blockIdx.x, h = threadIdx.x;
    __shared__ float mk[N_];
    for(int n=threadIdx.x;n<N_;n+=256) mk[n] = dmask[b*N_+n];
    __syncthreads();
    float s=0.f;
    #pragma unroll 8
    for(int n=0;n<N_;n++) s += mk[n]*vf[((size_t)b*N_+n)*H_ + h];
    sf[b*H_+h]=s;
}

// ======== S1: batched GEMV from sf: asw(k=0..3), s2m(m=4), ssf(m=5) ========
__global__ void k_s1(int d, const float* __restrict__ sf,
    const float* __restrict__ Was, const float* __restrict__ bas,
    const float* __restrict__ Wbmm,
    const float* __restrict__ Ws2m, const float* __restrict__ bs2m,
    const float* __restrict__ Wsup, const float* __restrict__ bsup,
    float* __restrict__ asw, float* __restrict__ s2m, float* __restrict__ ssf)
{
    int b = blockIdx.x, m = blockIdx.y, j = threadIdx.x;
    __shared__ float sfl[H_];
    sfl[j] = sf[b*H_+j];
    __syncthreads();
    const float* W; float bias;
    if (m < 4){ W = Was + (size_t)(d*K_+m)*H_*H_; bias = bas[(d*K_+m)*H_+j]; }
    else if (m==4){ W = Ws2m + (size_t)d*H_*H_; bias = bs2m[d*H_+j]; }
    else { W = Wsup + (size_t)d*H_*H_; bias = bsup[d*H_+j]; }
    float acc = bias;
    #pragma unroll 8
    for(int h=0;h<H_;h++) acc += sfl[h]*W[h*H_+j];
    float v = tanhf(acc);
    if (m < 4) asw[(b*K_+m)*H_+j] = v * Wbmm[(d*K_+m)*H_+j];
    else if (m==4) s2m[b*H_+j] = v;
    else ssf[b*H_+j] = v;
}

// ======== S2: stm2 partials (h-split by 4): stm2p[c][b][j] ========
__global__ void k_s2(int d, const float* __restrict__ s2m,
    const float* __restrict__ Wzm2, const float* __restrict__ bzm2,
    float* __restrict__ stm2p)
{
    int b=blockIdx.x, c=blockIdx.y, j=threadIdx.x;
    __shared__ float xl[64];
    if (j<64) xl[j] = s2m[b*H_ + c*64 + j];
    __syncthreads();
    const float* W = Wzm2 + (size_t)d*H_*H_ + (size_t)(c*64)*H_;
    float acc = (c==0) ? bzm2[d*H_+j] : 0.f;
    #pragma unroll 8
    for(int h=0;h<64;h++) acc += xl[h]*W[h*H_+j];
    stm2p[((size_t)c*B_+b)*H_+j] = acc;
}

// ================= MFMA core: A f32 (convert on stage), W from tiled bf16 WT =================
// WTg points at one matrix: [k0/32][n=0..255][32k] (8*256*32 u16 = H*H)
__device__ __forceinline__ void mfma_core_wt(const float* __restrict__ A,
    const u16* __restrict__ WTg, f32x4 acc[2][8],
    u16* __restrict__ Als, u16* __restrict__ Ws)
{
    const int LSA = 40, LSW = 40;
    int tid = threadIdx.x;
    int lane = tid & 63, wave = tid >> 6;
    int wy = wave >> 1, wx = wave & 1;
    int quad = lane >> 4, l15 = lane & 15;
    #pragma unroll
    for(int mt=0;mt<2;mt++)
        #pragma unroll
        for(int nt=0;nt<8;nt++) acc[mt][nt] = (f32x4){0.f,0.f,0.f,0.f};
    int arow = tid >> 2;
    int ak8  = (tid & 3) * 8;
    for(int k0=0;k0<H_;k0+=32){
        float4 a0 = *(const float4*)(A + (size_t)arow*H_ + k0 + ak8);
        float4 a1 = *(const float4*)(A + (size_t)arow*H_ + k0 + ak8 + 4);
        union { u16 u[8]; bf16x8 v; } ua;
        ua.u[0]=f2b(a0.x); ua.u[1]=f2b(a0.y); ua.u[2]=f2b(a0.z); ua.u[3]=f2b(a0.w);
        ua.u[4]=f2b(a1.x); ua.u[5]=f2b(a1.y); ua.u[6]=f2b(a1.z); ua.u[7]=f2b(a1.w);
        *(bf16x8*)(Als + arow*LSA + ak8) = ua.v;
        const u16* wsrc = WTg + (size_t)(k0>>5)*(256*32) + tid*32;
        #pragma unroll
        for(int c=0;c<4;c++)
            *(bf16x8*)(Ws + tid*LSW + c*8) = *(const bf16x8*)(wsrc + c*8);
        __syncthreads();
        bf16x8 af[2], bfr[8];
        #pragma unroll
        for(int mt=0;mt<2;mt++)
            af[mt] = *(const bf16x8*)(Als + (wy*32+mt*16+l15)*LSA + quad*8);
        #pragma unroll
        for(int nt=0;nt<8;nt++)
            bfr[nt] = *(const bf16x8*)(Ws + (wx*128+nt*16+l15)*LSW + quad*8);
        #pragma unroll
        for(int mt=0;mt<2;mt++)
            #pragma unroll
            for(int nt=0;nt<8;nt++)
                acc[mt][nt] = __builtin_amdgcn_mfma_f32_16x16x32_bf16(
                    af[mt], bfr[nt], acc[mt][nt], 0,0,0);
        __syncthreads();
    }
}

// ================= big GEMM over vf =================
__global__ __launch_bounds__(256) void k_gemm_big(int d, const float* __restrict__ vf,
    const u16* __restrict__ WT, const float* __restrict__ ba_main,
    const float* __restrict__ bbmm, const float* __restrict__ bu1,
    const float* __restrict__ asw, float* __restrict__ score,
    float* __restrict__ proj_u2, float* __restrict__ pu1a)
{
    __shared__ u16 Als[64*40];
    __shared__ u16 Ws[256*40];
    __shared__ float sred[64][33];
    int m0 = blockIdx.x*64;
    int seg = blockIdx.y;
    int b = m0 >> 9;
    int mi;
    if (seg < 4)      mi = d*4+seg;
    else if (seg==4)  mi = 12+d;
    else              mi = 15+d;
    f32x4 acc[2][8];
    mfma_core_wt(vf + (size_t)m0*H_, WT + (size_t)mi*H_*H_, acc, Als, Ws);
    int tid=threadIdx.x, lane=tid&63, wave=tid>>6;
    int wy=wave>>1, wx=wave&1, quad=lane>>4, l15=lane&15;
    if (seg < 4){
        const float* aswp = asw + (size_t)(b*K_+seg)*H_;
        const float* bap  = ba_main + (size_t)(d*K_+seg)*H_;
        float bbv[8], awv[8];
        #pragma unroll
        for(int nt=0;nt<8;nt++){
            int col = wx*128+nt*16+l15;
            bbv[nt]=bap[col]; awv[nt]=aswp[col];
        }
        #pragma unroll
        for(int mt=0;mt<2;mt++)
            #pragma unroll
            for(int r=0;r<4;r++){
                float p=0.f;
                #pragma unroll
                for(int nt=0;nt<8;nt++)
                    p += tanhf(acc[mt][nt][r]+bbv[nt])*awv[nt];
                int row = wy*32+mt*16+quad*4+r;
                sred[row][wx*16+l15] = p;
            }
        __syncthreads();
        if (tid < 64){
            float s=0.f;
            #pragma unroll 8
            for(int i=0;i<32;i++) s += sred[tid][i];
            score[(size_t)(b*K_+seg)*N_ + (m0&511) + tid] = s + bbmm[d*K_+seg];
        }
    } else if (seg==4){
        #pragma unroll
        for(int mt=0;mt<2;mt++)
            #pragma unroll
            for(int nt=0;nt<8;nt++){
                int col = wx*128+nt*16+l15;
                #pragma unroll
                for(int r=0;r<4;r++){
                    int row = m0 + wy*32+mt*16+quad*4+r;
                    proj_u2[(size_t)row*H_+col] = acc[mt][nt][r];
                }
            }
    } else {
        const float* bp = bu1 + d*H_;
        #pragma unroll
        for(int mt=0;mt<2;mt++)
            #pragma unroll
            for(int nt=0;nt<8;nt++){
                int col = wx*128+nt*16+l15;
                float bb = bp[col];
                #pragma unroll
                for(int r=0;r<4;r++){
                    int row = m0 + wy*32+mt*16+quad*4+r;
                    pu1a[(size_t)row*H_+col] = acc[mt][nt][r] + bb;
                }
            }
    }
}

// ===== main_self = lrelu(nei @ Wu1[H:] + pu, 0.1), in-place over pu =====
__global__ __launch_bounds__(256) void k_mainself(int d, const float* __restrict__ nei,
    const u16* __restrict__ WT, float* __restrict__ pu)
{
    __shared__ u16 Als[64*40];
    __shared__ u16 Ws[256*40];
    int m0 = blockIdx.x*64;
    f32x4 acc[2][8];
    mfma_core_wt(nei + (size_t)m0*H_, WT + (size_t)(18+d)*H_*H_, acc, Als, Ws);
    int tid=threadIdx.x, lane=tid&63, wave=tid>>6;
    int wy=wave>>1, wx=wave&1, quad=lane>>4, l15=lane&15;
    #pragma unroll
    for(int mt=0;mt<2;mt++)
        #pragma unroll
        for(int nt=0;nt<8;nt++){
            int col = wx*128+nt*16+l15;
            #pragma unroll
            for(int r=0;r<4;r++){
                int row = m0 + wy*32+mt*16+quad*4+r;
                float v = acc[mt][nt][r] + pu[(size_t)row*H_+col];
                v = v>0.f? v : 0.1f*v;
                pu[(size_t)row*H_+col] = v;
            }
        }
}

// ===== z_main GEMM + GRU vf update (stm2 from 4 partials) =====
__global__ __launch_bounds__(256) void k_update(int d, const float* __restrict__ main_self,
    const u16* __restrict__ WT, const float* __restrict__ bzm1,
    const float* __restrict__ stm2p, const float* __restrict__ s2m, float* __restrict__ vf)
{
    __shared__ u16 Als[64*40];
    __shared__ u16 Ws[256*40];
    int m0 = blockIdx.x*64; int b = m0>>9;
    f32x4 acc[2][8];
    mfma_core_wt(main_self + (size_t)m0*H_, WT + (size_t)(21+d)*H_*H_, acc, Als, Ws);
    int tid=threadIdx.x, lane=tid&63, wave=tid>>6;
    int wy=wave>>1, wx=wave&1, quad=lane>>4, l15=lane&15;
    #pragma unroll
    for(int mt=0;mt<2;mt++)
        #pragma unroll
        for(int nt=0;nt<8;nt++){
            int col = wx*128+nt*16+l15;
            float bz = bzm1[d*H_+col];
            float st = stm2p[(size_t)(0*B_+b)*H_+col] + stm2p[(size_t)(1*B_+b)*H_+col]
                     + stm2p[(size_t)(2*B_+b)*H_+col] + stm2p[(size_t)(3*B_+b)*H_+col];
            float sm = s2m[b*H_+col];
            #pragma unroll
            for(int r=0;r<4;r++){
                int row = m0 + wy*32+mt*16+quad*4+r;
                float z = sigmoidf_(acc[mt][nt][r] + bz + st);
                float ms = main_self[(size_t)row*H_+col];
                vf[(size_t)row*H_+col] = (1.f-z)*ms + z*sm;
            }
        }
}

// ---------------- masked softmax ----------------
__global__ void k_softmax(float* __restrict__ score, const float* __restrict__ dmask,
                          float* __restrict__ sumattn){
    int b = blockIdx.x, k = blockIdx.y;
    int tid = threadIdx.x;
    __shared__ float sh[256];
    float* a = score + (size_t)(b*K_+k)*N_;
    float v0 = a[tid], v1 = a[tid+256];
    sh[tid]=fmaxf(v0,v1); __syncthreads();
    for(int s=128;s>0;s>>=1){ if(tid<s) sh[tid]=fmaxf(sh[tid],sh[tid+s]); __syncthreads(); }
    float m = sh[0]; __syncthreads();
    float e0 = expf(v0-m)*dmask[b*N_+tid], e1 = expf(v1-m)*dmask[b*N_+tid+256];
    sh[tid]=e0+e1; __syncthreads();
    for(int s=128;s>0;s>>=1){ if(tid<s) sh[tid]+=sh[tid+s]; __syncthreads(); }
    float S = sh[0];
    float inv = 1.f/(S+1e-6f);
    a[tid]=e0*inv; a[tid+256]=e1*inv;
    if(tid==0) sumattn[b*K_+k]=S*inv;
}

// ======== t partials ========
__global__ void k_t2(const float* __restrict__ attn, const float* __restrict__ vf,
                     float* __restrict__ tpart){
    int b=blockIdx.x, k=blockIdx.y, c=blockIdx.z, h=threadIdx.x;
    __shared__ float at[256];
    at[h] = attn[(size_t)(b*K_+k)*N_ + c*256 + h];
    __syncthreads();
    float acc=0.f;
    const float* vfp = vf + ((size_t)b*N_ + c*256)*H_ + h;
    #pragma unroll 8
    for(int n=0;n<256;n++) acc += at[n]*vfp[(size_t)n*H_];
    tpart[((size_t)(c*B_+b)*K_+k)*H_+h]=acc;
}

// ======== M1: m2s ========
__global__ void k_m1(int d, const float* __restrict__ tpart, const float* __restrict__ sumattn,
    const float* __restrict__ Wm, const float* __restrict__ bm, float* __restrict__ m2s)
{
    int b=blockIdx.x, k=blockIdx.y, j=threadIdx.x;
    __shared__ float tl[H_];
    tl[j] = tpart[((size_t)(0*B_+b)*K_+k)*H_+j] + tpart[((size_t)(1*B_+b)*K_+k)*H_+j];
    __syncthreads();
    const float* W = Wm + (size_t)(d*K_+k)*H_*H_;
    float acc = sumattn[b*K_+k]*bm[(d*K_+k)*H_+j];
    #pragma unroll 8
    for(int h=0;h<H_;h++) acc += tl[h]*W[h*H_+j];
    m2s[(size_t)(b*K_+k)*H_+j]=acc;
}

// ======== M2: mts partials ========
__global__ void k_m2(int d, const float* __restrict__ m2s, const float* __restrict__ Wm2s,
                     float* __restrict__ mtsp)
{
    int b=blockIdx.x, c=blockIdx.y, j=threadIdx.x;
    __shared__ float xl[H_];
    xl[j]=m2s[(size_t)(b*K_+c)*H_+j];
    __syncthreads();
    const float* W = Wm2s + (size_t)d*(K_*H_)*H_ + (size_t)(c*H_)*H_;
    float acc=0.f;
    #pragma unroll 8
    for(int h=0;h<H_;h++) acc += xl[h]*W[h*H_+j];
    mtsp[((size_t)c*B_+b)*H_+j]=acc;
}

// ======== mts ========
__global__ void k_mts(int d, const float* __restrict__ mtsp, const float* __restrict__ bm2s,
                      float* __restrict__ mts){
    int b=blockIdx.x, j=threadIdx.x;
    float acc = bm2s[d*H_+j];
    #pragma unroll
    for(int c=0;c<4;c++) acc += mtsp[((size_t)c*B_+b)*H_+j];
    mts[b*H_+j]=tanhf(acc);
}

// ======== M3 ========
__global__ void k_m3(int d, const float* __restrict__ ssf, const float* __restrict__ mts,
    const float* __restrict__ Wzs1, const float* __restrict__ Wzs2,
    float* __restrict__ p1, float* __restrict__ p2)
{
    int b=blockIdx.x, m=blockIdx.y, j=threadIdx.x;
    __shared__ float xl[H_];
    const float* x = m ? mts : ssf;
    xl[j]=x[b*H_+j];
    __syncthreads();
    const float* W = (m ? Wzs2 : Wzs1) + (size_t)d*H_*H_;
    float acc=0.f;
    #pragma unroll 8
    for(int h=0;h<H_;h++) acc += xl[h]*W[h*H_+j];
    (m ? p2 : p1)[b*H_+j]=acc;
}

// ======== sf GRU update ========
__global__ void k_sfup(int d, const float* __restrict__ p1, const float* __restrict__ p2,
    const float* __restrict__ bzs1, const float* __restrict__ bzs2,
    const float* __restrict__ ssf, const float* __restrict__ mts, float* __restrict__ sf)
{
    int b=blockIdx.x, j=threadIdx.x;
    float z = sigmoidf_(p1[b*H_+j]+bzs1[d*H_+j]+p2[b*H_+j]+bzs2[d*H_+j]);
    sf[b*H_+j]=(1.f-z)*ssf[b*H_+j]+z*mts[b*H_+j];
}

// ---- nei ----
__global__ void k_nei(int d, const int* __restrict__ anb, const int* __restrict__ bnb,
    const float* __restrict__ nbm, const float* __restrict__ bond,
    const float* __restrict__ Wu2, const float* __restrict__ bu2,
    const float* __restrict__ proj_u2, float* __restrict__ nei)
{
    __shared__ float W2s[6][256];
    __shared__ float bfeat[NB_][6];
    __shared__ int ai[NB_]; __shared__ int bi[NB_]; __shared__ float mk[NB_];
    int row = blockIdx.x; int b = row >> 9; int h = threadIdx.x;
    const float* W2 = Wu2 + (size_t)d*(H_+6)*H_ + (size_t)H_*H_;
    for(int i=h;i<6*H_;i+=256) W2s[i>>8][i&255] = W2[i];
    if (h<NB_){ ai[h]=anb[row*NB_+h]; bi[h]=bnb[row*NB_+h]; mk[h]=nbm[row*NB_+h]; }
    __syncthreads();
    if (h<NB_*6){ int jn=h/6, i=h-jn*6; bfeat[jn][i]=bond[((size_t)b*E_+bi[jn])*6+i]; }
    __syncthreads();
    float bu = bu2[d*H_+h];
    float acc=0.f;
    #pragma unroll
    for(int jn=0;jn<NB_;jn++){
        float v = proj_u2[((size_t)b*N_+ai[jn])*H_+h] + bu;
        #pragma unroll
        for(int i=0;i<6;i++) v += bfeat[jn][i]*W2s[i][h];
        v = v>0.f? v : 0.1f*v;
        acc += mk[jn]*v;
    }
    nei[(size_t)row*H_+h]=acc;
}

// ---------------- final output ----------------
__global__ void k_out(const float* __restrict__ vf, const float* __restrict__ sf,
                      void* __restrict__ out, const int* __restrict__ flag){
    int idx = blockIdx.x*256 + threadIdx.x;
    const int total = M_*H_ + B_*H_;
    if (idx >= total) return;
    float v = (idx < M_*H_) ? vf[idx] : sf[idx - M_*H_];
    if (*flag) ((unsigned short*)out)[idx] = f2b(v);
    else       ((float*)out)[idx] = v;
}

extern "C" void kernel_launch(void* const* d_in, const int* in_sizes, int n_in,
                              void* d_out, int out_size, void* d_ws, size_t ws_size,
                              hipStream_t stream)
{
    const int* anb = (const int*)d_in[2];
    const int* bnb = (const int*)d_in[3];

    float* ws   = (float*)d_ws;
    int*   flag = (int*)ws;                 // 256 B reserved
    float* cvt  = ws + 64;
    float* p    = cvt + ((CVT_OFF.v[31] + 63) & ~63L);
    float* vf        = p; p += (size_t)M_*H_;
    float* proj_u2   = p; p += (size_t)M_*H_;
    float* proj_u1a  = p; p += (size_t)M_*H_;   // becomes main_self in-place
    float* nei       = p; p += (size_t)M_*H_;
    float* sf        = p; p += B_*H_;
    float* score     = p; p += B_*K_*N_;
    float* sumattn   = p; p += B_*K_;
    float* asw       = p; p += B_*K_*H_;
    float* s2m       = p; p += B_*H_;
    float* ssf       = p; p += B_*H_;
    float* stm2p     = p; p += 4*B_*H_;
    float* tpart     = p; p += 2*B_*K_*H_;
    float* m2s       = p; p += B_*K_*H_;
    float* mtsp      = p; p += 4*B_*H_;
    float* mts       = p; p += B_*H_;
    float* p1        = p; p += B_*H_;
    float* p2        = p; p += B_*H_;
    u16*   WT        = (u16*)p;             // 24 * H*H bf16 = 3.1 MB

    const float* cBond = cvt + CVT_OFF.v[0];
    const float* cNbm  = cvt + CVT_OFF.v[1];
    const float* cDm   = cvt + CVT_OFF.v[2];
    const float* cWv   = cvt + CVT_OFF.v[3];
    const float* cbv   = cvt + CVT_OFF.v[4];
    const float* cWam  = cvt + CVT_OFF.v[5];
    const float* cbam  = cvt + CVT_OFF.v[6];
    const float* cWas  = cvt + CVT_OFF.v[7];
    const float* cbas  = cvt + CVT_OFF.v[8];
    const float* cWm   = cvt + CVT_OFF.v[9];
    const float* cbm   = cvt + CVT_OFF.v[10];
    const float* cWbmm = cvt + CVT_OFF.v[11];
    const float* cbbmm = cvt + CVT_OFF.v[12];
    const float* cWm2s = cvt + CVT_OFF.v[13];
    const float* cbm2s = cvt + CVT_OFF.v[14];
    const float* cWs2m = cvt + CVT_OFF.v[15];
    const float* cbs2m = cvt + CVT_OFF.v[16];
    const float* cWsup = cvt + CVT_OFF.v[17];
    const float* cbsup = cvt + CVT_OFF.v[18];
    const float* cWzm1 = cvt + CVT_OFF.v[19];
    const float* cbzm1 = cvt + CVT_OFF.v[20];
    const float* cWzm2 = cvt + CVT_OFF.v[21];
    const float* cbzm2 = cvt + CVT_OFF.v[22];
    const float* cWzs1 = cvt + CVT_OFF.v[23];
    const float* cbzs1 = cvt + CVT_OFF.v[24];
    const float* cWzs2 = cvt + CVT_OFF.v[25];
    const float* cbzs2 = cvt + CVT_OFF.v[26];
    const float* cWu2  = cvt + CVT_OFF.v[27];
    const float* cbu2  = cvt + CVT_OFF.v[28];
    const float* cWu1  = cvt + CVT_OFF.v[29];
    const float* cbu1  = cvt + CVT_OFF.v[30];

    Ptrs ptrs;
    {
        int idx[31] = {1,4,5,6,7,8,9,10,11,12,13,14,15,16,17,18,19,20,21,
                       22,23,24,25,26,27,28,29,30,31,32,33};
        for(int i=0;i<31;i++) ptrs.p[i] = d_in[idx[i]];
    }

    k_detect<<<1,64,0,stream>>>((const unsigned short*)d_in[6], flag);
    {
        int maxv4 = (D_*K_*H_*H_ + 3)/4;
        int gx = (maxv4 + 255)/256;
        k_cvt<<<dim3(gx,31),256,0,stream>>>(ptrs, cvt, flag);
    }
    k_wt<<<dim3(8,8,24),dim3(32,8),0,stream>>>(cWam, cWu2, cWu1, cWzm1, WT);

    k_embed<<<M_/8,256,0,stream>>>((const u16*)d_in[0], cWv, cbv, vf, flag);
    k_sf0<<<B_,256,0,stream>>>(vf, cDm, sf);
    for(int d=0; d<D_; d++){
        k_s1<<<dim3(B_,6),256,0,stream>>>(d, sf, cWas, cbas, cWbmm,
                                          cWs2m, cbs2m, cWsup, cbsup, asw, s2m, ssf);
        k_s2<<<dim3(B_,4),256,0,stream>>>(d, s2m, cWzm2, cbzm2, stm2p);
        k_gemm_big<<<dim3(M_/64,6),256,0,stream>>>(d, vf, WT, cbam, cbbmm, cbu1,
                                                   asw, score, proj_u2, proj_u1a);
        k_softmax<<<dim3(B_,K_),256,0,stream>>>(score, cDm, sumattn);
        k_t2<<<dim3(B_,K_,2),256,0,stream>>>(score, vf, tpart);
        k_m1<<<dim3(B_,K_),256,0,stream>>>(d, tpart, sumattn, cWm, cbm, m2s);
        k_m2<<<dim3(B_,4),256,0,stream>>>(d, m2s, cWm2s, mtsp);
        k_mts<<<B_,256,0,stream>>>(d, mtsp, cbm2s, mts);
        k_m3<<<dim3(B_,2),256,0,stream>>>(d, ssf, mts, cWzs1, cWzs2, p1, p2);
        k_sfup<<<B_,256,0,stream>>>(d, p1, p2, cbzs1, cbzs2, ssf, mts, sf);
        k_nei<<<M_,256,0,stream>>>(d, anb, bnb, cNbm, cBond, cWu2, cbu2, proj_u2, nei);
        k_mainself<<<M_/64,256,0,stream>>>(d, nei, WT, proj_u1a);
        k_update<<<M_/64,256,0,stream>>>(d, proj_u1a, WT, cbzm1, stm2p, s2m, vf);
    }
    k_out<<<(M_*H_+B_*H_+255)/256,256,0,stream>>>(vf, sf, d_out, flag);
}